// Round 6
// baseline (3519.057 us; speedup 1.0000x reference)
//
#include <hip/hip_runtime.h>

// ---- problem constants ----
#define BT      32768     // B*T = 128*256
#define T_SEQ   256
#define E_DIM   384
#define NH      6
#define NL      6
#define VOC     65
#define FF_DIM  1536
#define QKV_N   1152      // 3*E

typedef short bf16x8 __attribute__((ext_vector_type(8)));   // 8 bf16 (4 VGPRs)
typedef float f32x4  __attribute__((ext_vector_type(4)));
typedef unsigned short u16;

__device__ __forceinline__ u16 f2bf(float x) {              // RNE fp32->bf16
  unsigned u = __builtin_bit_cast(unsigned, x);
  u += 0x7fffu + ((u >> 16) & 1u);
  return (u16)(u >> 16);
}
__device__ __forceinline__ float bf2f(u16 v) {
  unsigned u = ((unsigned)v) << 16;
  return __builtin_bit_cast(float, u);
}

// raw workgroup barrier: waits LDS ops only; leaves global loads in flight
// (__syncthreads would emit s_waitcnt vmcnt(0) and drain the prefetch - the R3 stall)
__device__ __forceinline__ void lds_barrier() {
  asm volatile("s_waitcnt lgkmcnt(0)\n\ts_barrier" ::: "memory");
}

// ---------------- unified LDS-tiled transpose: src[b][R][C] fp32 -> dst bf16 [.. C][R] ----------------
__global__ __launch_bounds__(256) void transpose_t(
    const float* __restrict__ src, u16* __restrict__ dst, int R, int C,
    long sbs, long dbs_outer, int inner, long dbs_inner, long dbase) {
  __shared__ float t[32][33];
  const int b = blockIdx.z;
  const float* s = src + (long)b * sbs;
  u16* d = dst + dbase + (long)(b / inner) * dbs_outer + (long)(b % inner) * dbs_inner;
  const int r0 = blockIdx.x * 32, c0 = blockIdx.y * 32;
  const int tx = threadIdx.x & 31, ty = threadIdx.x >> 5;   // 32 x 8
#pragma unroll
  for (int i = 0; i < 4; i++) {
    int rr = ty + i * 8;
    int r = r0 + rr, c = c0 + tx;
    if (r < R && c < C) t[rr][tx] = s[(long)r * C + c];
  }
  __syncthreads();
#pragma unroll
  for (int i = 0; i < 4; i++) {
    int cc = ty + i * 8;
    int c = c0 + cc, r = r0 + tx;
    if (c < C && r < R) d[(long)c * R + r] = f2bf(t[tx][cc]);
  }
}

// ---------------- embedding (bf16 out) ----------------
__global__ __launch_bounds__(256) void embed_k(const int* __restrict__ idx,
                                               const float* __restrict__ tok,
                                               const float* __restrict__ pos,
                                               u16* __restrict__ x) {
  int i = blockIdx.x * 256 + threadIdx.x;        // over BT*48 groups of 8
  int bt = i / 48, q = i - bt * 48;
  int t = bt & 255;
  const float4* tp = (const float4*)(tok + (size_t)idx[bt] * E_DIM + q * 8);
  const float4* pp = (const float4*)(pos + (size_t)t * E_DIM + q * 8);
  float4 a0 = tp[0], a1 = tp[1], p0 = pp[0], p1 = pp[1];
  u16 o[8];
  o[0] = f2bf(a0.x + p0.x); o[1] = f2bf(a0.y + p0.y);
  o[2] = f2bf(a0.z + p0.z); o[3] = f2bf(a0.w + p0.w);
  o[4] = f2bf(a1.x + p1.x); o[5] = f2bf(a1.y + p1.y);
  o[6] = f2bf(a1.z + p1.z); o[7] = f2bf(a1.w + p1.w);
  *(bf16x8*)(x + (size_t)bt * E_DIM + q * 8) = *(bf16x8*)o;
}

// ---------------- layernorm (bf16 in -> bf16 out, fp32 math) ----------------
__global__ __launch_bounds__(256) void ln_k(const u16* __restrict__ x,
                                            const float* __restrict__ gam,
                                            const float* __restrict__ bet,
                                            u16* __restrict__ out) {
  int tid = threadIdx.x, lane = tid & 63, w = tid >> 6;
  size_t token = (size_t)blockIdx.x * 4 + w;
  const u16* xr = x + token * E_DIM;
  u16 raw[6];
  *(uint2*)raw          = *(const uint2*)(xr + 4 * lane);
  *(unsigned*)(raw + 4) = *(const unsigned*)(xr + 256 + 2 * lane);
  float v[6]; float s = 0.f;
#pragma unroll
  for (int i = 0; i < 6; i++) { v[i] = bf2f(raw[i]); s += v[i]; }
#pragma unroll
  for (int d = 1; d < 64; d <<= 1) s += __shfl_xor(s, d);
  float mean = s * (1.f / E_DIM);
  float q = 0.f;
#pragma unroll
  for (int i = 0; i < 6; i++) { float d0 = v[i] - mean; q += d0 * d0; }
#pragma unroll
  for (int d = 1; d < 64; d <<= 1) q += __shfl_xor(q, d);
  float r = rsqrtf(q * (1.f / E_DIM) + 1e-5f);
  int e[6] = {4 * lane, 4 * lane + 1, 4 * lane + 2, 4 * lane + 3,
              256 + 2 * lane, 256 + 2 * lane + 1};
  u16 o[6];
#pragma unroll
  for (int i = 0; i < 6; i++)
    o[i] = f2bf((v[i] - mean) * r * gam[e[i]] + bet[e[i]]);
  u16* orow = out + token * E_DIM;
  *(uint2*)(orow + 4 * lane)          = *(uint2*)o;
  *(unsigned*)(orow + 256 + 2 * lane) = *(unsigned*)(o + 4);
}

// ---------------- pipelined MFMA GEMM: C[M][N] = A[M][K](bf16) @ Bt[N][K](bf16)^T ------
// 128x128 tile, BK=32, 4 waves 2x2 (64x64 each). Register-staged double-buffered LDS:
//   iter k: ds_write regs(tile k+1) -> buf nxt   (vmcnt wait here, after prior compute)
//           issue global loads tile k+2 -> regs  (stay in flight across the barrier)
//           compute from buf cur (8x ds_read_b128 + 16 MFMA)
//           lds_barrier()                        (lgkmcnt only - no vmem drain)
// LDS rows padded to 34 elems (conflict-free); possible because we ds_write (not DMA).
__global__ __launch_bounds__(256) void gemm_p(
    const u16* __restrict__ A, const u16* __restrict__ Bt, int K, int Nstore,
    const float* __restrict__ bias, const u16* __restrict__ resid,
    u16* __restrict__ outH, float* __restrict__ outF, int relu) {
  __shared__ u16 smem[17408];                 // A0|A1|B0|B1, each 128*34
  const int tid = threadIdx.x, lane = tid & 63, wv = tid >> 6;
  const int quad = lane >> 4, l16 = lane & 15;
  const int m0 = blockIdx.x * 128, n0 = blockIdx.y * 128;
  const int wm = (wv & 1) * 64, wn = (wv >> 1) * 64;

  // staging map: idx = tid + j*256 (j=0,1) -> row = idx>>2 (0..127), seg = (idx&3)*8 elems
  const int srow0 = tid >> 2, scol = (tid & 3) * 8;   // j=0 rows 0..63
  const int srow1 = srow0 + 64;                        // j=1 rows 64..127
  const u16* ApG0 = A  + (size_t)(m0 + srow0) * K + scol;
  const u16* ApG1 = A  + (size_t)(m0 + srow1) * K + scol;
  const u16* BpG0 = Bt + (size_t)(n0 + srow0) * K + scol;
  const u16* BpG1 = Bt + (size_t)(n0 + srow1) * K + scol;
  const int wofs0 = srow0 * 34 + scol, wofs1 = srow1 * 34 + scol;

  f32x4 acc[4][4];
#pragma unroll
  for (int i = 0; i < 4; i++)
#pragma unroll
    for (int j = 0; j < 4; j++) acc[i][j] = (f32x4){0.f, 0.f, 0.f, 0.f};

  uint4 ra0, ra1, rb0, rb1;                   // staging regs (one tile)
  // prologue: tile0 -> buf0
  ra0 = *(const uint4*)ApG0; ra1 = *(const uint4*)ApG1;
  rb0 = *(const uint4*)BpG0; rb1 = *(const uint4*)BpG1;
  *(uint4*)&smem[wofs0] = ra0; *(uint4*)&smem[wofs1] = ra1;
  *(uint4*)&smem[8704 + wofs0] = rb0; *(uint4*)&smem[8704 + wofs1] = rb1;
  // load tile1
  ra0 = *(const uint4*)(ApG0 + 32); ra1 = *(const uint4*)(ApG1 + 32);
  rb0 = *(const uint4*)(BpG0 + 32); rb1 = *(const uint4*)(BpG1 + 32);
  lds_barrier();

  const int NK = K >> 5;
  for (int kt = 0; kt < NK; kt++) {
    const int cur = kt & 1, nxt = cur ^ 1;
    if (kt + 1 < NK) {                        // write tile kt+1 (vmcnt wait lands here)
      *(uint4*)&smem[nxt * 4352 + wofs0] = ra0;
      *(uint4*)&smem[nxt * 4352 + wofs1] = ra1;
      *(uint4*)&smem[8704 + nxt * 4352 + wofs0] = rb0;
      *(uint4*)&smem[8704 + nxt * 4352 + wofs1] = rb1;
    }
    if (kt + 2 < NK) {                        // issue tile kt+2 (in flight across barrier)
      const int k2 = (kt + 2) * 32;
      ra0 = *(const uint4*)(ApG0 + k2); ra1 = *(const uint4*)(ApG1 + k2);
      rb0 = *(const uint4*)(BpG0 + k2); rb1 = *(const uint4*)(BpG1 + k2);
    }
    const u16* Ab = smem + cur * 4352;
    const u16* Bb = smem + 8704 + cur * 4352;
    bf16x8 af[4], bfr[4];
#pragma unroll
    for (int i = 0; i < 4; i++) af[i]  = *(const bf16x8*)&Ab[(wm + i * 16 + l16) * 34 + quad * 8];
#pragma unroll
    for (int j = 0; j < 4; j++) bfr[j] = *(const bf16x8*)&Bb[(wn + j * 16 + l16) * 34 + quad * 8];
#pragma unroll
    for (int i = 0; i < 4; i++)
#pragma unroll
      for (int j = 0; j < 4; j++)
        acc[i][j] = __builtin_amdgcn_mfma_f32_16x16x32_bf16(af[i], bfr[j], acc[i][j], 0, 0, 0);
    lds_barrier();
  }

  if (outH) {
    // 4 passes of 32 cols: deposit C-layout into cbuf[128][36] (pad 36), sweep coalesced.
#pragma unroll
    for (int p = 0; p < 4; p++) {
      if (p) __syncthreads();
      if ((wv >> 1) == (p >> 1)) {
#pragma unroll
        for (int jj = 0; jj < 2; jj++) {
          int j = (p & 1) * 2 + jj;
          int gn = n0 + wn + j * 16 + l16;
          float bv = bias ? bias[gn] : 0.f;
          int lcol = jj * 16 + l16;
#pragma unroll
          for (int i = 0; i < 4; i++)
#pragma unroll
            for (int r = 0; r < 4; r++) {
              float v = acc[i][j][r] + bv;
              if (relu) v = fmaxf(v, 0.f);
              smem[(wm + i * 16 + quad * 4 + r) * 36 + lcol] = f2bf(v);
            }
        }
      }
      __syncthreads();
      const int gc0 = n0 + p * 32;
#pragma unroll
      for (int s = 0; s < 4; s++) {
        int row = s * 32 + (tid >> 3);
        int seg = (tid & 7) * 4;
        u16 pk[4];
        *(uint2*)pk = *(const uint2*)&smem[row * 36 + seg];
        size_t o = (size_t)(m0 + row) * Nstore + gc0 + seg;
        if (resid) {
          u16 rv[4];
          *(uint2*)rv = *(const uint2*)&resid[o];
#pragma unroll
          for (int q2 = 0; q2 < 4; q2++) pk[q2] = f2bf(bf2f(pk[q2]) + bf2f(rv[q2]));
        }
        *(uint2*)&outH[o] = *(uint2*)pk;
      }
    }
  } else {
    // fp32 path (logits, N=65)
#pragma unroll
    for (int j = 0; j < 4; j++) {
      const int gn = n0 + wn + j * 16 + l16;
      if (gn < Nstore) {
        const float bv = bias ? bias[gn] : 0.f;
#pragma unroll
        for (int i = 0; i < 4; i++)
#pragma unroll
          for (int r = 0; r < 4; r++) {
            const int gm = m0 + wm + i * 16 + quad * 4 + r;
            outF[(size_t)gm * Nstore + gn] = acc[i][j][r] + bv;
          }
      }
    }
  }
}

// ---------------- fused causal attention ----------------
__global__ __launch_bounds__(512) void attn_k(const u16* __restrict__ qkv,
                                              u16* __restrict__ att) {
  __shared__ u16 Kc[64 * 64];
  __shared__ u16 Vtc[64 * 64];
  __shared__ u16 Pl[8 * 32 * 64];
  const int b = blockIdx.x / NH, h = blockIdx.x % NH;
  const int tid = threadIdx.x, lane = tid & 63, w = tid >> 6;
  const int quad = lane >> 4, l16 = lane & 15;
  const int rowb = b * T_SEQ;

  bf16x8 qf[2][2];
#pragma unroll
  for (int mi = 0; mi < 2; mi++)
#pragma unroll
    for (int kk = 0; kk < 2; kk++)
      qf[mi][kk] = *(const bf16x8*)(qkv + (size_t)(rowb + w * 32 + mi * 16 + l16) * QKV_N +
                                    h * 64 + kk * 32 + quad * 8);

  f32x4 Oa[2][4];
  float mrun[2][4], lrun[2][4];
#pragma unroll
  for (int mi = 0; mi < 2; mi++) {
#pragma unroll
    for (int di = 0; di < 4; di++) Oa[mi][di] = (f32x4){0.f, 0.f, 0.f, 0.f};
#pragma unroll
    for (int r = 0; r < 4; r++) { mrun[mi][r] = -1e30f; lrun[mi][r] = 0.f; }
  }

  u16* Pw = &Pl[w * 2048];
  const int nch = (w >> 1) + 1;
  const int sr = tid >> 3, sseg = (tid & 7) * 8;

  for (int c = 0; c < 4; c++) {
    const int s0 = c * 64;
    __syncthreads();
    *(uint4*)&Kc[sr * 64 + sseg] =
        *(const uint4*)(qkv + (size_t)(rowb + s0 + sr) * QKV_N + 384 + h * 64 + sseg);
    {
      union { uint4 u; u16 us[8]; } tb;
      tb.u = *(const uint4*)(qkv + (size_t)(rowb + s0 + sr) * QKV_N + 768 + h * 64 + sseg);
#pragma unroll
      for (int j = 0; j < 8; j++) Vtc[(sseg + j) * 64 + sr] = tb.us[j];
    }
    __syncthreads();
    if (c >= nch) continue;

    f32x4 S[2][4];
    bf16x8 kf[4][2];
#pragma unroll
    for (int ni = 0; ni < 4; ni++)
#pragma unroll
      for (int kk = 0; kk < 2; kk++)
        kf[ni][kk] = *(const bf16x8*)&Kc[(ni * 16 + l16) * 64 + kk * 32 + quad * 8];
#pragma unroll
    for (int mi = 0; mi < 2; mi++)
#pragma unroll
      for (int ni = 0; ni < 4; ni++) {
        f32x4 z = (f32x4){0.f, 0.f, 0.f, 0.f};
        z = __builtin_amdgcn_mfma_f32_16x16x32_bf16(qf[mi][0], kf[ni][0], z, 0, 0, 0);
        S[mi][ni] = __builtin_amdgcn_mfma_f32_16x16x32_bf16(qf[mi][1], kf[ni][1], z, 0, 0, 0);
      }
    const bool diag = (c == nch - 1);
#pragma unroll
    for (int mi = 0; mi < 2; mi++)
#pragma unroll
      for (int ni = 0; ni < 4; ni++)
#pragma unroll
        for (int r = 0; r < 4; r++) {
          float xv = S[mi][ni][r] * 0.125f;
          if (diag) {
            int t = w * 32 + mi * 16 + quad * 4 + r;
            int s = s0 + ni * 16 + l16;
            if (s > t) xv = -1e30f;
          }
          S[mi][ni][r] = xv;
        }
#pragma unroll
    for (int mi = 0; mi < 2; mi++)
#pragma unroll
      for (int r = 0; r < 4; r++) {
        float mx = fmaxf(fmaxf(S[mi][0][r], S[mi][1][r]), fmaxf(S[mi][2][r], S[mi][3][r]));
        mx = fmaxf(mx, __shfl_xor(mx, 1));
        mx = fmaxf(mx, __shfl_xor(mx, 2));
        mx = fmaxf(mx, __shfl_xor(mx, 4));
        mx = fmaxf(mx, __shfl_xor(mx, 8));
        float mnew = fmaxf(mrun[mi][r], mx);
        float alpha = __expf(mrun[mi][r] - mnew);
        float ls = 0.f;
#pragma unroll
        for (int ni = 0; ni < 4; ni++) {
          float p = __expf(S[mi][ni][r] - mnew);
          S[mi][ni][r] = p; ls += p;
        }
        ls += __shfl_xor(ls, 1); ls += __shfl_xor(ls, 2);
        ls += __shfl_xor(ls, 4); ls += __shfl_xor(ls, 8);
        lrun[mi][r] = lrun[mi][r] * alpha + ls;
        mrun[mi][r] = mnew;
#pragma unroll
        for (int di = 0; di < 4; di++) Oa[mi][di][r] *= alpha;
      }
#pragma unroll
    for (int mi = 0; mi < 2; mi++)
#pragma unroll
      for (int ni = 0; ni < 4; ni++)
#pragma unroll
        for (int r = 0; r < 4; r++)
          Pw[(mi * 16 + quad * 4 + r) * 64 + ni * 16 + l16] = f2bf(S[mi][ni][r]);
    bf16x8 pf[2][2], vf[4][2];
#pragma unroll
    for (int mi = 0; mi < 2; mi++)
#pragma unroll
      for (int kk = 0; kk < 2; kk++)
        pf[mi][kk] = *(const bf16x8*)&Pw[(mi * 16 + l16) * 64 + kk * 32 + quad * 8];
#pragma unroll
    for (int di = 0; di < 4; di++)
#pragma unroll
      for (int kk = 0; kk < 2; kk++)
        vf[di][kk] = *(const bf16x8*)&Vtc[(di * 16 + l16) * 64 + kk * 32 + quad * 8];
#pragma unroll
    for (int mi = 0; mi < 2; mi++)
#pragma unroll
      for (int di = 0; di < 4; di++) {
        Oa[mi][di] = __builtin_amdgcn_mfma_f32_16x16x32_bf16(pf[mi][0], vf[di][0], Oa[mi][di], 0, 0, 0);
        Oa[mi][di] = __builtin_amdgcn_mfma_f32_16x16x32_bf16(pf[mi][1], vf[di][1], Oa[mi][di], 0, 0, 0);
      }
  }

#pragma unroll
  for (int mi = 0; mi < 2; mi++)
#pragma unroll
    for (int r = 0; r < 4; r++) {
      float inv = 1.f / lrun[mi][r];
      int t = w * 32 + mi * 16 + quad * 4 + r;
#pragma unroll
      for (int di = 0; di < 4; di++)
        att[(size_t)(rowb + t) * E_DIM + h * 64 + di * 16 + l16] = f2bf(Oa[mi][di][r] * inv);
    }
}

// ---------------- loss: grid-stride, 1 atomic per block ----------------
__global__ __launch_bounds__(256) void loss_k(const float* __restrict__ logits,
                                              const int* __restrict__ tgt,
                                              float* __restrict__ loss) {
  __shared__ float part[4];
  const int tid = threadIdx.x, lane = tid & 63, w = tid >> 6;
  const int wave_id = blockIdx.x * 4 + w;          // 512 blocks -> 2048 waves
  float acc = 0.f;
  for (int t = wave_id; t < BT; t += 2048) {
    const float* row = logits + (size_t)t * VOC;
    float a = row[lane];
    float b = (lane == 0) ? row[64] : -1e30f;
    float mx = fmaxf(a, b);
#pragma unroll
    for (int d = 1; d < 64; d <<= 1) mx = fmaxf(mx, __shfl_xor(mx, d));
    float sum = __expf(a - mx) + ((lane == 0) ? __expf(b - mx) : 0.f);
#pragma unroll
    for (int d = 1; d < 64; d <<= 1) sum += __shfl_xor(sum, d);
    if (lane == 0) acc += mx + __logf(sum) - row[tgt[t]];
  }
  if (lane == 0) part[w] = acc;
  __syncthreads();
  if (tid == 0)
    atomicAdd(loss, (part[0] + part[1] + part[2] + part[3]) * (1.f / (float)BT));
}

// ---------------- host ----------------
extern "C" void kernel_launch(void* const* d_in, const int* in_sizes, int n_in,
                              void* d_out, int out_size, void* d_ws, size_t ws_size,
                              hipStream_t stream) {
  (void)in_sizes; (void)n_in; (void)out_size; (void)ws_size;
  const int*   idx  = (const int*)d_in[0];
  const int*   tgt  = (const int*)d_in[1];
  const float* tok  = (const float*)d_in[2];
  const float* pos  = (const float*)d_in[3];
  const float* Wq   = (const float*)d_in[4];
  const float* Wk   = (const float*)d_in[5];
  const float* Wv   = (const float*)d_in[6];
  const float* Wo   = (const float*)d_in[7];
  const float* bo   = (const float*)d_in[8];
  const float* ln1s = (const float*)d_in[9];
  const float* ln1b = (const float*)d_in[10];
  const float* ln2s = (const float*)d_in[11];
  const float* ln2b = (const float*)d_in[12];
  const float* W1   = (const float*)d_in[13];
  const float* b1   = (const float*)d_in[14];
  const float* W2   = (const float*)d_in[15];
  const float* b2   = (const float*)d_in[16];
  const float* lnfs = (const float*)d_in[17];
  const float* lnfb = (const float*)d_in[18];
  const float* Wout = (const float*)d_in[19];
  const float* bout = (const float*)d_in[20];

  char* w = (char*)d_ws;
  u16* x      = (u16*)w;    w += (size_t)BT * E_DIM * 2;      // bf16 residual stream
  u16* hb     = (u16*)w;    w += (size_t)BT * E_DIM * 2;
  u16* attb   = (u16*)w;    w += (size_t)BT * E_DIM * 2;
  u16* big    = (u16*)w;    w += (size_t)BT * FF_DIM * 2;     // qkv / ff union
  u16* Wqkv_t = (u16*)w;    w += (size_t)NL * QKV_N * E_DIM * 2;
  u16* Wo_t   = (u16*)w;    w += (size_t)NL * E_DIM * E_DIM * 2;
  u16* W1_t   = (u16*)w;    w += (size_t)NL * FF_DIM * E_DIM * 2;
  u16* W2_t   = (u16*)w;    w += (size_t)NL * E_DIM * FF_DIM * 2;
  u16* Wout_t = (u16*)w;    w += (size_t)128 * E_DIM * 2;
  u16* qkv = big;
  u16* ff  = big;

  float* logits = (float*)d_out;
  float* loss   = logits + (size_t)BT * VOC;

  hipMemsetAsync(Wout_t, 0, 128 * E_DIM * 2, stream);
  transpose_t<<<dim3(12, 2, 36), 256, 0, stream>>>(Wq, Wqkv_t, 384, 64,
      24576, 442368, 6, 24576, 0);
  transpose_t<<<dim3(12, 2, 36), 256, 0, stream>>>(Wk, Wqkv_t, 384, 64,
      24576, 442368, 6, 24576, (long)384 * 384);
  transpose_t<<<dim3(12, 2, 36), 256, 0, stream>>>(Wv, Wqkv_t, 384, 64,
      24576, 442368, 6, 24576, (long)768 * 384);
  transpose_t<<<dim3(12, 12, 6), 256, 0, stream>>>(Wo, Wo_t, 384, 384,
      147456, 147456, 1, 0, 0);
  transpose_t<<<dim3(12, 48, 6), 256, 0, stream>>>(W1, W1_t, 384, 1536,
      589824, 589824, 1, 0, 0);
  transpose_t<<<dim3(48, 12, 6), 256, 0, stream>>>(W2, W2_t, 1536, 384,
      589824, 589824, 1, 0, 0);
  transpose_t<<<dim3(12, 3, 1), 256, 0, stream>>>(Wout, Wout_t, 384, 65,
      0, 0, 1, 0, 0);

  embed_k<<<6144, 256, 0, stream>>>(idx, tok, pos, x);

  for (int l = 0; l < NL; l++) {
    ln_k<<<8192, 256, 0, stream>>>(x, ln1s + l * E_DIM, ln1b + l * E_DIM, hb);
    gemm_p<<<dim3(256, 9), 256, 0, stream>>>(hb, Wqkv_t + (size_t)l * QKV_N * E_DIM,
                                             384, QKV_N, nullptr, nullptr, qkv, nullptr, 0);
    attn_k<<<768, 512, 0, stream>>>(qkv, attb);
    gemm_p<<<dim3(256, 3), 256, 0, stream>>>(attb, Wo_t + (size_t)l * E_DIM * E_DIM,
                                             384, E_DIM, bo + l * E_DIM, x, x, nullptr, 0);
    ln_k<<<8192, 256, 0, stream>>>(x, ln2s + l * E_DIM, ln2b + l * E_DIM, hb);
    gemm_p<<<dim3(256, 12), 256, 0, stream>>>(hb, W1_t + (size_t)l * FF_DIM * E_DIM,
                                              384, FF_DIM, b1 + l * FF_DIM, nullptr, ff, nullptr, 1);
    gemm_p<<<dim3(256, 3), 256, 0, stream>>>(ff, W2_t + (size_t)l * E_DIM * FF_DIM,
                                             1536, E_DIM, b2 + l * E_DIM, x, x, nullptr, 0);
  }
  ln_k<<<8192, 256, 0, stream>>>(x, lnfs, lnfb, hb);
  gemm_p<<<dim3(256, 1), 256, 0, stream>>>(hb, Wout_t, 384, VOC, bout, nullptr, nullptr, logits, 0);

  hipMemsetAsync(loss, 0, 4, stream);
  loss_k<<<512, 256, 0, stream>>>(logits, tgt, loss);
}

// Round 7
// 2302.953 us; speedup vs baseline: 1.5281x; 1.5281x over previous
//
#include <hip/hip_runtime.h>

// ---- problem constants ----
#define BT      32768     // B*T = 128*256
#define T_SEQ   256
#define E_DIM   384
#define NH      6
#define NL      6
#define VOC     65
#define FF_DIM  1536
#define QKV_N   1152      // 3*E

typedef short bf16x8 __attribute__((ext_vector_type(8)));   // 8 bf16 (4 VGPRs)
typedef float f32x4  __attribute__((ext_vector_type(4)));
typedef unsigned short u16;

typedef const unsigned int __attribute__((address_space(1))) gu32;
typedef unsigned int       __attribute__((address_space(3))) lu32;

__device__ __forceinline__ u16 f2bf(float x) {              // RNE fp32->bf16
  unsigned u = __builtin_bit_cast(unsigned, x);
  u += 0x7fffu + ((u >> 16) & 1u);
  return (u16)(u >> 16);
}
__device__ __forceinline__ float bf2f(u16 v) {
  unsigned u = ((unsigned)v) << 16;
  return __builtin_bit_cast(float, u);
}

__device__ __forceinline__ void load_lds_16(const void* g, void* l) {
  __builtin_amdgcn_global_load_lds((gu32*)g, (lu32*)l, 16, 0, 0);
}

// ---------------- unified LDS-tiled transpose: src[b][R][C] fp32 -> dst bf16 [.. C][R] ----------------
__global__ __launch_bounds__(256) void transpose_t(
    const float* __restrict__ src, u16* __restrict__ dst, int R, int C,
    long sbs, long dbs_outer, int inner, long dbs_inner, long dbase) {
  __shared__ float t[32][33];
  const int b = blockIdx.z;
  const float* s = src + (long)b * sbs;
  u16* d = dst + dbase + (long)(b / inner) * dbs_outer + (long)(b % inner) * dbs_inner;
  const int r0 = blockIdx.x * 32, c0 = blockIdx.y * 32;
  const int tx = threadIdx.x & 31, ty = threadIdx.x >> 5;   // 32 x 8
#pragma unroll
  for (int i = 0; i < 4; i++) {
    int rr = ty + i * 8;
    int r = r0 + rr, c = c0 + tx;
    if (r < R && c < C) t[rr][tx] = s[(long)r * C + c];
  }
  __syncthreads();
#pragma unroll
  for (int i = 0; i < 4; i++) {
    int cc = ty + i * 8;
    int c = c0 + cc, r = r0 + tx;
    if (c < C && r < R) d[(long)c * R + r] = f2bf(t[tx][cc]);
  }
}

// ---------------- embedding (bf16 out) ----------------
__global__ __launch_bounds__(256) void embed_k(const int* __restrict__ idx,
                                               const float* __restrict__ tok,
                                               const float* __restrict__ pos,
                                               u16* __restrict__ x) {
  int i = blockIdx.x * 256 + threadIdx.x;        // over BT*48 groups of 8
  int bt = i / 48, q = i - bt * 48;
  int t = bt & 255;
  const float4* tp = (const float4*)(tok + (size_t)idx[bt] * E_DIM + q * 8);
  const float4* pp = (const float4*)(pos + (size_t)t * E_DIM + q * 8);
  float4 a0 = tp[0], a1 = tp[1], p0 = pp[0], p1 = pp[1];
  u16 o[8];
  o[0] = f2bf(a0.x + p0.x); o[1] = f2bf(a0.y + p0.y);
  o[2] = f2bf(a0.z + p0.z); o[3] = f2bf(a0.w + p0.w);
  o[4] = f2bf(a1.x + p1.x); o[5] = f2bf(a1.y + p1.y);
  o[6] = f2bf(a1.z + p1.z); o[7] = f2bf(a1.w + p1.w);
  *(bf16x8*)(x + (size_t)bt * E_DIM + q * 8) = *(bf16x8*)o;
}

// ---------------- layernorm (bf16 in -> bf16 out, fp32 math) ----------------
__global__ __launch_bounds__(256) void ln_k(const u16* __restrict__ x,
                                            const float* __restrict__ gam,
                                            const float* __restrict__ bet,
                                            u16* __restrict__ out) {
  int tid = threadIdx.x, lane = tid & 63, w = tid >> 6;
  size_t token = (size_t)blockIdx.x * 4 + w;
  const u16* xr = x + token * E_DIM;
  u16 raw[6];
  *(uint2*)raw          = *(const uint2*)(xr + 4 * lane);
  *(unsigned*)(raw + 4) = *(const unsigned*)(xr + 256 + 2 * lane);
  float v[6]; float s = 0.f;
#pragma unroll
  for (int i = 0; i < 6; i++) { v[i] = bf2f(raw[i]); s += v[i]; }
#pragma unroll
  for (int d = 1; d < 64; d <<= 1) s += __shfl_xor(s, d);
  float mean = s * (1.f / E_DIM);
  float q = 0.f;
#pragma unroll
  for (int i = 0; i < 6; i++) { float d0 = v[i] - mean; q += d0 * d0; }
#pragma unroll
  for (int d = 1; d < 64; d <<= 1) q += __shfl_xor(q, d);
  float r = rsqrtf(q * (1.f / E_DIM) + 1e-5f);
  int e[6] = {4 * lane, 4 * lane + 1, 4 * lane + 2, 4 * lane + 3,
              256 + 2 * lane, 256 + 2 * lane + 1};
  u16 o[6];
#pragma unroll
  for (int i = 0; i < 6; i++)
    o[i] = f2bf((v[i] - mean) * r * gam[e[i]] + bet[e[i]]);
  u16* orow = out + token * E_DIM;
  *(uint2*)(orow + 4 * lane)          = *(uint2*)o;
  *(unsigned*)(orow + 256 + 2 * lane) = *(unsigned*)(o + 4);
}

// ---------------- swizzled DMA-staged MFMA GEMM: C = A[M][K] @ Bt[N][K]^T (bf16) ------
// 128x128 tile, BK=64, single-buffered 32KB LDS (-> ~5 blocks/CU for block-level
// latency overlap), 4 waves 2x2 (64x64/wave), 32 MFMA between barriers (2/iter, 6
// iters at K=384). Staging via global_load_lds (no VGPR round trip). LDS layout is
// XOR-swizzled AT THE GLOBAL SOURCE: chunk c (16B) of row r lands at slot c^(r&7),
// so fragment ds_read_b128s hit 8 distinct 4-bank groups (2-way only = free),
// while global reads stay within the same 128B segment (fully coalesced).
__global__ __launch_bounds__(256) void gemm_s(
    const u16* __restrict__ A, const u16* __restrict__ Bt, int K, int Nstore,
    const float* __restrict__ bias, const u16* __restrict__ resid,
    u16* __restrict__ outH, float* __restrict__ outF, int relu) {
  __shared__ u16 smem[16384];                 // As[128][64] | Bs[128][64]
  u16* As = smem;
  u16* Bs = smem + 8192;
  const int tid = threadIdx.x, lane = tid & 63, wv = tid >> 6;
  const int quad = lane >> 4, l16 = lane & 15;
  const int m0 = blockIdx.x * 128, n0 = blockIdx.y * 128;
  const int wm = (wv & 1) * 64, wn = (wv >> 1) * 64;

  // staging: each instr covers 8 rows (8 lanes/row of 16B); lane -> (row, swz chunk)
  const int lrow = lane >> 3;                  // 0..7
  const int lchunk = (lane & 7) ^ lrow;        // swizzled source chunk 0..7
  const int rswz = l16 & 7;                    // fragment-read swizzle key

  f32x4 acc[4][4];
#pragma unroll
  for (int i = 0; i < 4; i++)
#pragma unroll
    for (int j = 0; j < 4; j++) acc[i][j] = (f32x4){0.f, 0.f, 0.f, 0.f};

  const int NK = K >> 6;
  for (int kt = 0; kt < NK; kt++) {
    const int k0 = kt << 6;
    __syncthreads();                           // WAR: prior reads done before overwrite
#pragma unroll
    for (int j = 0; j < 4; j++) {              // A: 16 row-groups of 8, 4 per wave
      int rid = wv * 4 + j;
      load_lds_16(A + (size_t)(m0 + rid * 8 + lrow) * K + k0 + lchunk * 8, &As[rid * 512]);
    }
#pragma unroll
    for (int j = 0; j < 4; j++) {              // B: same
      int rid = wv * 4 + j;
      load_lds_16(Bt + (size_t)(n0 + rid * 8 + lrow) * K + k0 + lchunk * 8, &Bs[rid * 512]);
    }
    __syncthreads();                           // RAW: staging complete
#pragma unroll
    for (int ks = 0; ks < 2; ks++) {
      bf16x8 af[4], bfr[4];
#pragma unroll
      for (int i = 0; i < 4; i++)
        af[i] = *(const bf16x8*)&As[(wm + i * 16 + l16) * 64 + (((ks << 2) | quad) ^ rswz) * 8];
#pragma unroll
      for (int j = 0; j < 4; j++)
        bfr[j] = *(const bf16x8*)&Bs[(wn + j * 16 + l16) * 64 + (((ks << 2) | quad) ^ rswz) * 8];
#pragma unroll
      for (int i = 0; i < 4; i++)
#pragma unroll
        for (int j = 0; j < 4; j++)
          acc[i][j] = __builtin_amdgcn_mfma_f32_16x16x32_bf16(af[i], bfr[j], acc[i][j], 0, 0, 0);
    }
  }

  if (outH) {
    // 4 passes of 32 cols: deposit C-layout into cbuf[128][36] (pad 36), sweep coalesced.
#pragma unroll
    for (int p = 0; p < 4; p++) {
      __syncthreads();
      if ((wv >> 1) == (p >> 1)) {
#pragma unroll
        for (int jj = 0; jj < 2; jj++) {
          int j = (p & 1) * 2 + jj;
          int gn = n0 + wn + j * 16 + l16;
          float bv = bias ? bias[gn] : 0.f;
          int lcol = jj * 16 + l16;
#pragma unroll
          for (int i = 0; i < 4; i++)
#pragma unroll
            for (int r = 0; r < 4; r++) {
              float v = acc[i][j][r] + bv;
              if (relu) v = fmaxf(v, 0.f);
              smem[(wm + i * 16 + quad * 4 + r) * 36 + lcol] = f2bf(v);
            }
        }
      }
      __syncthreads();
      const int gc0 = n0 + p * 32;
#pragma unroll
      for (int s = 0; s < 4; s++) {
        int row = s * 32 + (tid >> 3);
        int seg = (tid & 7) * 4;
        u16 pk[4];
        *(uint2*)pk = *(const uint2*)&smem[row * 36 + seg];
        size_t o = (size_t)(m0 + row) * Nstore + gc0 + seg;
        if (resid) {
          u16 rv[4];
          *(uint2*)rv = *(const uint2*)&resid[o];
#pragma unroll
          for (int q2 = 0; q2 < 4; q2++) pk[q2] = f2bf(bf2f(pk[q2]) + bf2f(rv[q2]));
        }
        *(uint2*)&outH[o] = *(uint2*)pk;
      }
    }
  } else {
    // fp32 path (logits, N=65)
#pragma unroll
    for (int j = 0; j < 4; j++) {
      const int gn = n0 + wn + j * 16 + l16;
      if (gn < Nstore) {
        const float bv = bias ? bias[gn] : 0.f;
#pragma unroll
        for (int i = 0; i < 4; i++)
#pragma unroll
          for (int r = 0; r < 4; r++) {
            const int gm = m0 + wm + i * 16 + quad * 4 + r;
            outF[(size_t)gm * Nstore + gn] = acc[i][j][r] + bv;
          }
      }
    }
  }
}

// ---------------- fused causal attention ----------------
__global__ __launch_bounds__(512) void attn_k(const u16* __restrict__ qkv,
                                              u16* __restrict__ att) {
  __shared__ u16 Kc[64 * 64];
  __shared__ u16 Vtc[64 * 64];
  __shared__ u16 Pl[8 * 32 * 64];
  const int b = blockIdx.x / NH, h = blockIdx.x % NH;
  const int tid = threadIdx.x, lane = tid & 63, w = tid >> 6;
  const int quad = lane >> 4, l16 = lane & 15;
  const int rowb = b * T_SEQ;

  bf16x8 qf[2][2];
#pragma unroll
  for (int mi = 0; mi < 2; mi++)
#pragma unroll
    for (int kk = 0; kk < 2; kk++)
      qf[mi][kk] = *(const bf16x8*)(qkv + (size_t)(rowb + w * 32 + mi * 16 + l16) * QKV_N +
                                    h * 64 + kk * 32 + quad * 8);

  f32x4 Oa[2][4];
  float mrun[2][4], lrun[2][4];
#pragma unroll
  for (int mi = 0; mi < 2; mi++) {
#pragma unroll
    for (int di = 0; di < 4; di++) Oa[mi][di] = (f32x4){0.f, 0.f, 0.f, 0.f};
#pragma unroll
    for (int r = 0; r < 4; r++) { mrun[mi][r] = -1e30f; lrun[mi][r] = 0.f; }
  }

  u16* Pw = &Pl[w * 2048];
  const int nch = (w >> 1) + 1;
  const int sr = tid >> 3, sseg = (tid & 7) * 8;

  for (int c = 0; c < 4; c++) {
    const int s0 = c * 64;
    __syncthreads();
    *(uint4*)&Kc[sr * 64 + sseg] =
        *(const uint4*)(qkv + (size_t)(rowb + s0 + sr) * QKV_N + 384 + h * 64 + sseg);
    {
      union { uint4 u; u16 us[8]; } tb;
      tb.u = *(const uint4*)(qkv + (size_t)(rowb + s0 + sr) * QKV_N + 768 + h * 64 + sseg);
#pragma unroll
      for (int j = 0; j < 8; j++) Vtc[(sseg + j) * 64 + sr] = tb.us[j];
    }
    __syncthreads();
    if (c >= nch) continue;

    f32x4 S[2][4];
    bf16x8 kf[4][2];
#pragma unroll
    for (int ni = 0; ni < 4; ni++)
#pragma unroll
      for (int kk = 0; kk < 2; kk++)
        kf[ni][kk] = *(const bf16x8*)&Kc[(ni * 16 + l16) * 64 + kk * 32 + quad * 8];
#pragma unroll
    for (int mi = 0; mi < 2; mi++)
#pragma unroll
      for (int ni = 0; ni < 4; ni++) {
        f32x4 z = (f32x4){0.f, 0.f, 0.f, 0.f};
        z = __builtin_amdgcn_mfma_f32_16x16x32_bf16(qf[mi][0], kf[ni][0], z, 0, 0, 0);
        S[mi][ni] = __builtin_amdgcn_mfma_f32_16x16x32_bf16(qf[mi][1], kf[ni][1], z, 0, 0, 0);
      }
    const bool diag = (c == nch - 1);
#pragma unroll
    for (int mi = 0; mi < 2; mi++)
#pragma unroll
      for (int ni = 0; ni < 4; ni++)
#pragma unroll
        for (int r = 0; r < 4; r++) {
          float xv = S[mi][ni][r] * 0.125f;
          if (diag) {
            int t = w * 32 + mi * 16 + quad * 4 + r;
            int s = s0 + ni * 16 + l16;
            if (s > t) xv = -1e30f;
          }
          S[mi][ni][r] = xv;
        }
#pragma unroll
    for (int mi = 0; mi < 2; mi++)
#pragma unroll
      for (int r = 0; r < 4; r++) {
        float mx = fmaxf(fmaxf(S[mi][0][r], S[mi][1][r]), fmaxf(S[mi][2][r], S[mi][3][r]));
        mx = fmaxf(mx, __shfl_xor(mx, 1));
        mx = fmaxf(mx, __shfl_xor(mx, 2));
        mx = fmaxf(mx, __shfl_xor(mx, 4));
        mx = fmaxf(mx, __shfl_xor(mx, 8));
        float mnew = fmaxf(mrun[mi][r], mx);
        float alpha = __expf(mrun[mi][r] - mnew);
        float ls = 0.f;
#pragma unroll
        for (int ni = 0; ni < 4; ni++) {
          float p = __expf(S[mi][ni][r] - mnew);
          S[mi][ni][r] = p; ls += p;
        }
        ls += __shfl_xor(ls, 1); ls += __shfl_xor(ls, 2);
        ls += __shfl_xor(ls, 4); ls += __shfl_xor(ls, 8);
        lrun[mi][r] = lrun[mi][r] * alpha + ls;
        mrun[mi][r] = mnew;
#pragma unroll
        for (int di = 0; di < 4; di++) Oa[mi][di][r] *= alpha;
      }
#pragma unroll
    for (int mi = 0; mi < 2; mi++)
#pragma unroll
      for (int ni = 0; ni < 4; ni++)
#pragma unroll
        for (int r = 0; r < 4; r++)
          Pw[(mi * 16 + quad * 4 + r) * 64 + ni * 16 + l16] = f2bf(S[mi][ni][r]);
    bf16x8 pf[2][2], vf[4][2];
#pragma unroll
    for (int mi = 0; mi < 2; mi++)
#pragma unroll
      for (int kk = 0; kk < 2; kk++)
        pf[mi][kk] = *(const bf16x8*)&Pw[(mi * 16 + l16) * 64 + kk * 32 + quad * 8];
#pragma unroll
    for (int di = 0; di < 4; di++)
#pragma unroll
      for (int kk = 0; kk < 2; kk++)
        vf[di][kk] = *(const bf16x8*)&Vtc[(di * 16 + l16) * 64 + kk * 32 + quad * 8];
#pragma unroll
    for (int mi = 0; mi < 2; mi++)
#pragma unroll
      for (int di = 0; di < 4; di++) {
        Oa[mi][di] = __builtin_amdgcn_mfma_f32_16x16x32_bf16(pf[mi][0], vf[di][0], Oa[mi][di], 0, 0, 0);
        Oa[mi][di] = __builtin_amdgcn_mfma_f32_16x16x32_bf16(pf[mi][1], vf[di][1], Oa[mi][di], 0, 0, 0);
      }
  }

#pragma unroll
  for (int mi = 0; mi < 2; mi++)
#pragma unroll
    for (int r = 0; r < 4; r++) {
      float inv = 1.f / lrun[mi][r];
      int t = w * 32 + mi * 16 + quad * 4 + r;
#pragma unroll
      for (int di = 0; di < 4; di++)
        att[(size_t)(rowb + t) * E_DIM + h * 64 + di * 16 + l16] = f2bf(Oa[mi][di][r] * inv);
    }
}

// ---------------- loss: grid-stride, 1 atomic per block ----------------
__global__ __launch_bounds__(256) void loss_k(const float* __restrict__ logits,
                                              const int* __restrict__ tgt,
                                              float* __restrict__ loss) {
  __shared__ float part[4];
  const int tid = threadIdx.x, lane = tid & 63, w = tid >> 6;
  const int wave_id = blockIdx.x * 4 + w;          // 512 blocks -> 2048 waves
  float acc = 0.f;
  for (int t = wave_id; t < BT; t += 2048) {
    const float* row = logits + (size_t)t * VOC;
    float a = row[lane];
    float b = (lane == 0) ? row[64] : -1e30f;
    float mx = fmaxf(a, b);
#pragma unroll
    for (int d = 1; d < 64; d <<= 1) mx = fmaxf(mx, __shfl_xor(mx, d));
    float sum = __expf(a - mx) + ((lane == 0) ? __expf(b - mx) : 0.f);
#pragma unroll
    for (int d = 1; d < 64; d <<= 1) sum += __shfl_xor(sum, d);
    if (lane == 0) acc += mx + __logf(sum) - row[tgt[t]];
  }
  if (lane == 0) part[w] = acc;
  __syncthreads();
  if (tid == 0)
    atomicAdd(loss, (part[0] + part[1] + part[2] + part[3]) * (1.f / (float)BT));
}

// ---------------- host ----------------
extern "C" void kernel_launch(void* const* d_in, const int* in_sizes, int n_in,
                              void* d_out, int out_size, void* d_ws, size_t ws_size,
                              hipStream_t stream) {
  (void)in_sizes; (void)n_in; (void)out_size; (void)ws_size;
  const int*   idx  = (const int*)d_in[0];
  const int*   tgt  = (const int*)d_in[1];
  const float* tok  = (const float*)d_in[2];
  const float* pos  = (const float*)d_in[3];
  const float* Wq   = (const float*)d_in[4];
  const float* Wk   = (const float*)d_in[5];
  const float* Wv   = (const float*)d_in[6];
  const float* Wo   = (const float*)d_in[7];
  const float* bo   = (const float*)d_in[8];
  const float* ln1s = (const float*)d_in[9];
  const float* ln1b = (const float*)d_in[10];
  const float* ln2s = (const float*)d_in[11];
  const float* ln2b = (const float*)d_in[12];
  const float* W1   = (const float*)d_in[13];
  const float* b1   = (const float*)d_in[14];
  const float* W2   = (const float*)d_in[15];
  const float* b2   = (const float*)d_in[16];
  const float* lnfs = (const float*)d_in[17];
  const float* lnfb = (const float*)d_in[18];
  const float* Wout = (const float*)d_in[19];
  const float* bout = (const float*)d_in[20];

  char* w = (char*)d_ws;
  u16* x      = (u16*)w;    w += (size_t)BT * E_DIM * 2;      // bf16 residual stream
  u16* hb     = (u16*)w;    w += (size_t)BT * E_DIM * 2;
  u16* attb   = (u16*)w;    w += (size_t)BT * E_DIM * 2;
  u16* big    = (u16*)w;    w += (size_t)BT * FF_DIM * 2;     // qkv / ff union
  u16* Wqkv_t = (u16*)w;    w += (size_t)NL * QKV_N * E_DIM * 2;
  u16* Wo_t   = (u16*)w;    w += (size_t)NL * E_DIM * E_DIM * 2;
  u16* W1_t   = (u16*)w;    w += (size_t)NL * FF_DIM * E_DIM * 2;
  u16* W2_t   = (u16*)w;    w += (size_t)NL * E_DIM * FF_DIM * 2;
  u16* Wout_t = (u16*)w;    w += (size_t)128 * E_DIM * 2;
  u16* qkv = big;
  u16* ff  = big;

  float* logits = (float*)d_out;
  float* loss   = logits + (size_t)BT * VOC;

  hipMemsetAsync(Wout_t, 0, 128 * E_DIM * 2, stream);
  transpose_t<<<dim3(12, 2, 36), 256, 0, stream>>>(Wq, Wqkv_t, 384, 64,
      24576, 442368, 6, 24576, 0);
  transpose_t<<<dim3(12, 2, 36), 256, 0, stream>>>(Wk, Wqkv_t, 384, 64,
      24576, 442368, 6, 24576, (long)384 * 384);
  transpose_t<<<dim3(12, 2, 36), 256, 0, stream>>>(Wv, Wqkv_t, 384, 64,
      24576, 442368, 6, 24576, (long)768 * 384);
  transpose_t<<<dim3(12, 12, 6), 256, 0, stream>>>(Wo, Wo_t, 384, 384,
      147456, 147456, 1, 0, 0);
  transpose_t<<<dim3(12, 48, 6), 256, 0, stream>>>(W1, W1_t, 384, 1536,
      589824, 589824, 1, 0, 0);
  transpose_t<<<dim3(48, 12, 6), 256, 0, stream>>>(W2, W2_t, 1536, 384,
      589824, 589824, 1, 0, 0);
  transpose_t<<<dim3(12, 3, 1), 256, 0, stream>>>(Wout, Wout_t, 384, 65,
      0, 0, 1, 0, 0);

  embed_k<<<6144, 256, 0, stream>>>(idx, tok, pos, x);

  for (int l = 0; l < NL; l++) {
    ln_k<<<8192, 256, 0, stream>>>(x, ln1s + l * E_DIM, ln1b + l * E_DIM, hb);
    gemm_s<<<dim3(256, 9), 256, 0, stream>>>(hb, Wqkv_t + (size_t)l * QKV_N * E_DIM,
                                             384, QKV_N, nullptr, nullptr, qkv, nullptr, 0);
    attn_k<<<768, 512, 0, stream>>>(qkv, attb);
    gemm_s<<<dim3(256, 3), 256, 0, stream>>>(attb, Wo_t + (size_t)l * E_DIM * E_DIM,
                                             384, E_DIM, bo + l * E_DIM, x, x, nullptr, 0);
    ln_k<<<8192, 256, 0, stream>>>(x, ln2s + l * E_DIM, ln2b + l * E_DIM, hb);
    gemm_s<<<dim3(256, 12), 256, 0, stream>>>(hb, W1_t + (size_t)l * FF_DIM * E_DIM,
                                              384, FF_DIM, b1 + l * FF_DIM, nullptr, ff, nullptr, 1);
    gemm_s<<<dim3(256, 3), 256, 0, stream>>>(ff, W2_t + (size_t)l * E_DIM * FF_DIM,
                                             1536, E_DIM, b2 + l * E_DIM, x, x, nullptr, 0);
  }
  ln_k<<<8192, 256, 0, stream>>>(x, lnfs, lnfb, hb);
  gemm_s<<<dim3(256, 1), 256, 0, stream>>>(hb, Wout_t, 384, VOC, bout, nullptr, nullptr, logits, 0);

  hipMemsetAsync(loss, 0, 4, stream);
  loss_k<<<512, 256, 0, stream>>>(logits, tgt, loss);
}

// Round 8
// 1801.436 us; speedup vs baseline: 1.9535x; 1.2784x over previous
//
#include <hip/hip_runtime.h>

// ---- problem constants ----
#define BT      32768     // B*T = 128*256
#define T_SEQ   256
#define E_DIM   384
#define NH      6
#define NL      6
#define VOC     65
#define FF_DIM  1536
#define QKV_N   1152      // 3*E

typedef short bf16x8 __attribute__((ext_vector_type(8)));   // 8 bf16 (4 VGPRs)
typedef float f32x4  __attribute__((ext_vector_type(4)));
typedef unsigned short u16;

typedef const unsigned int __attribute__((address_space(1))) gu32;
typedef unsigned int       __attribute__((address_space(3))) lu32;

__device__ __forceinline__ u16 f2bf(float x) {              // RNE fp32->bf16
  unsigned u = __builtin_bit_cast(unsigned, x);
  u += 0x7fffu + ((u >> 16) & 1u);
  return (u16)(u >> 16);
}
__device__ __forceinline__ float bf2f(u16 v) {
  unsigned u = ((unsigned)v) << 16;
  return __builtin_bit_cast(float, u);
}

__device__ __forceinline__ void load_lds_16(const void* g, void* l) {
  __builtin_amdgcn_global_load_lds((gu32*)g, (lu32*)l, 16, 0, 0);
}

// ---------------- unified LDS-tiled transpose: src[b][R][C] fp32 -> dst bf16 [.. C][R] ----------------
__global__ __launch_bounds__(256) void transpose_t(
    const float* __restrict__ src, u16* __restrict__ dst, int R, int C,
    long sbs, long dbs_outer, int inner, long dbs_inner, long dbase) {
  __shared__ float t[32][33];
  const int b = blockIdx.z;
  const float* s = src + (long)b * sbs;
  u16* d = dst + dbase + (long)(b / inner) * dbs_outer + (long)(b % inner) * dbs_inner;
  const int r0 = blockIdx.x * 32, c0 = blockIdx.y * 32;
  const int tx = threadIdx.x & 31, ty = threadIdx.x >> 5;   // 32 x 8
#pragma unroll
  for (int i = 0; i < 4; i++) {
    int rr = ty + i * 8;
    int r = r0 + rr, c = c0 + tx;
    if (r < R && c < C) t[rr][tx] = s[(long)r * C + c];
  }
  __syncthreads();
#pragma unroll
  for (int i = 0; i < 4; i++) {
    int cc = ty + i * 8;
    int c = c0 + cc, r = r0 + tx;
    if (c < C && r < R) d[(long)c * R + r] = f2bf(t[tx][cc]);
  }
}

// ---------------- embedding (bf16 out) ----------------
__global__ __launch_bounds__(256) void embed_k(const int* __restrict__ idx,
                                               const float* __restrict__ tok,
                                               const float* __restrict__ pos,
                                               u16* __restrict__ x) {
  int i = blockIdx.x * 256 + threadIdx.x;        // over BT*48 groups of 8
  int bt = i / 48, q = i - bt * 48;
  int t = bt & 255;
  const float4* tp = (const float4*)(tok + (size_t)idx[bt] * E_DIM + q * 8);
  const float4* pp = (const float4*)(pos + (size_t)t * E_DIM + q * 8);
  float4 a0 = tp[0], a1 = tp[1], p0 = pp[0], p1 = pp[1];
  u16 o[8];
  o[0] = f2bf(a0.x + p0.x); o[1] = f2bf(a0.y + p0.y);
  o[2] = f2bf(a0.z + p0.z); o[3] = f2bf(a0.w + p0.w);
  o[4] = f2bf(a1.x + p1.x); o[5] = f2bf(a1.y + p1.y);
  o[6] = f2bf(a1.z + p1.z); o[7] = f2bf(a1.w + p1.w);
  *(bf16x8*)(x + (size_t)bt * E_DIM + q * 8) = *(bf16x8*)o;
}

// ---------------- layernorm (bf16 in -> bf16 out, fp32 math) ----------------
__global__ __launch_bounds__(256) void ln_k(const u16* __restrict__ x,
                                            const float* __restrict__ gam,
                                            const float* __restrict__ bet,
                                            u16* __restrict__ out) {
  int tid = threadIdx.x, lane = tid & 63, w = tid >> 6;
  size_t token = (size_t)blockIdx.x * 4 + w;
  const u16* xr = x + token * E_DIM;
  u16 raw[6];
  *(uint2*)raw          = *(const uint2*)(xr + 4 * lane);
  *(unsigned*)(raw + 4) = *(const unsigned*)(xr + 256 + 2 * lane);
  float v[6]; float s = 0.f;
#pragma unroll
  for (int i = 0; i < 6; i++) { v[i] = bf2f(raw[i]); s += v[i]; }
#pragma unroll
  for (int d = 1; d < 64; d <<= 1) s += __shfl_xor(s, d);
  float mean = s * (1.f / E_DIM);
  float q = 0.f;
#pragma unroll
  for (int i = 0; i < 6; i++) { float d0 = v[i] - mean; q += d0 * d0; }
#pragma unroll
  for (int d = 1; d < 64; d <<= 1) q += __shfl_xor(q, d);
  float r = rsqrtf(q * (1.f / E_DIM) + 1e-5f);
  int e[6] = {4 * lane, 4 * lane + 1, 4 * lane + 2, 4 * lane + 3,
              256 + 2 * lane, 256 + 2 * lane + 1};
  u16 o[6];
#pragma unroll
  for (int i = 0; i < 6; i++)
    o[i] = f2bf((v[i] - mean) * r * gam[e[i]] + bet[e[i]]);
  u16* orow = out + token * E_DIM;
  *(uint2*)(orow + 4 * lane)          = *(uint2*)o;
  *(unsigned*)(orow + 256 + 2 * lane) = *(unsigned*)(o + 4);
}

// ---------------- dbuf + swizzled DMA MFMA GEMM: C = A[M][K] @ Bt[N][K]^T (bf16) ------
// 128x128 tile, BK=32, DOUBLE-buffered DMA staging (prefetch tile k+1 before compute
// of tile k -> one barrier/iter, drain overlapped with compute: R3's win) PLUS
// source-side XOR swizzle (chunk c of row r lands at slot c^(r&3): conflict-free
// fragment reads AND conflict-free DMA writes: R6's win). 32KB LDS, 4 waves 2x2.
__global__ __launch_bounds__(256) void gemm_d(
    const u16* __restrict__ A, const u16* __restrict__ Bt, int K, int Nstore,
    const float* __restrict__ bias, const u16* __restrict__ resid,
    u16* __restrict__ outH, float* __restrict__ outF, int relu) {
  __shared__ u16 smem[16384];                 // As[2][128][32] | Bs[2][128][32]
  u16* As = smem;
  u16* Bs = smem + 8192;
  const int tid = threadIdx.x, lane = tid & 63, wv = tid >> 6;
  const int quad = lane >> 4, l16 = lane & 15;
  const int m0 = blockIdx.x * 128, n0 = blockIdx.y * 128;
  const int wm = (wv & 1) * 64, wn = (wv >> 1) * 64;

  // staging: each DMA instr covers 16 rows x 4 chunks(16B); lane -> (row, swz chunk)
  const int lrow = lane >> 2;                  // row within 16-row group
  const int lchunk = (lane & 3) ^ (lrow & 3);  // swizzled source chunk
  const int rs = quad == 0 ? 0 : quad;         // (kept simple; see read below)

  f32x4 acc[4][4];
#pragma unroll
  for (int i = 0; i < 4; i++)
#pragma unroll
    for (int j = 0; j < 4; j++) acc[i][j] = (f32x4){0.f, 0.f, 0.f, 0.f};

  auto stage = [&](int sel, int k0) {
#pragma unroll
    for (int j = 0; j < 2; j++) {
      int rid = wv * 2 + j;                    // 8 groups of 16 rows
      int r = rid * 16 + lrow;
      load_lds_16(A + (size_t)(m0 + r) * K + k0 + lchunk * 8, &As[sel * 4096 + rid * 512]);
      load_lds_16(Bt + (size_t)(n0 + r) * K + k0 + lchunk * 8, &Bs[sel * 4096 + rid * 512]);
    }
  };

  const int NK = K >> 5;
  stage(0, 0);
  __syncthreads();                             // drain prologue DMA
  for (int kt = 0; kt < NK; kt++) {
    const int cur = kt & 1;
    if (kt + 1 < NK) stage(cur ^ 1, (kt + 1) * 32);  // prefetch; drain at loop barrier
    const u16* Ab = As + cur * 4096;
    const u16* Bb = Bs + cur * 4096;
    const int slot = (quad ^ (l16 & 3)) * 8;   // un-swizzle for fragment read
    bf16x8 af[4], bfr[4];
#pragma unroll
    for (int i = 0; i < 4; i++) af[i]  = *(const bf16x8*)&Ab[(wm + i * 16 + l16) * 32 + slot];
#pragma unroll
    for (int j = 0; j < 4; j++) bfr[j] = *(const bf16x8*)&Bb[(wn + j * 16 + l16) * 32 + slot];
#pragma unroll
    for (int i = 0; i < 4; i++)
#pragma unroll
      for (int j = 0; j < 4; j++)
        acc[i][j] = __builtin_amdgcn_mfma_f32_16x16x32_bf16(af[i], bfr[j], acc[i][j], 0, 0, 0);
    __syncthreads();   // drains prefetch (after compute overlap) + guards dbuf reuse
  }

  if (outH) {
    // 4 passes of 32 cols: deposit C-layout into cbuf[128][36] (pad 36), sweep coalesced.
#pragma unroll
    for (int p = 0; p < 4; p++) {
      if (p) __syncthreads();
      if ((wv >> 1) == (p >> 1)) {
#pragma unroll
        for (int jj = 0; jj < 2; jj++) {
          int j = (p & 1) * 2 + jj;
          int gn = n0 + wn + j * 16 + l16;
          float bv = bias ? bias[gn] : 0.f;
          int lcol = jj * 16 + l16;
#pragma unroll
          for (int i = 0; i < 4; i++)
#pragma unroll
            for (int r = 0; r < 4; r++) {
              float v = acc[i][j][r] + bv;
              if (relu) v = fmaxf(v, 0.f);
              smem[(wm + i * 16 + quad * 4 + r) * 36 + lcol] = f2bf(v);
            }
        }
      }
      __syncthreads();
      const int gc0 = n0 + p * 32;
#pragma unroll
      for (int s = 0; s < 4; s++) {
        int row = s * 32 + (tid >> 3);
        int seg = (tid & 7) * 4;
        u16 pk[4];
        *(uint2*)pk = *(const uint2*)&smem[row * 36 + seg];
        size_t o = (size_t)(m0 + row) * Nstore + gc0 + seg;
        if (resid) {
          u16 rv[4];
          *(uint2*)rv = *(const uint2*)&resid[o];
#pragma unroll
          for (int q2 = 0; q2 < 4; q2++) pk[q2] = f2bf(bf2f(pk[q2]) + bf2f(rv[q2]));
        }
        *(uint2*)&outH[o] = *(uint2*)pk;
      }
    }
  } else {
    // fp32 path (logits, N=65)
#pragma unroll
    for (int j = 0; j < 4; j++) {
      const int gn = n0 + wn + j * 16 + l16;
      if (gn < Nstore) {
        const float bv = bias ? bias[gn] : 0.f;
#pragma unroll
        for (int i = 0; i < 4; i++)
#pragma unroll
          for (int r = 0; r < 4; r++) {
            const int gm = m0 + wm + i * 16 + quad * 4 + r;
            outF[(size_t)gm * Nstore + gn] = acc[i][j][r] + bv;
          }
      }
    }
  }
}

// ---------------- fused causal attention ----------------
__global__ __launch_bounds__(512) void attn_k(const u16* __restrict__ qkv,
                                              u16* __restrict__ att) {
  __shared__ u16 Kc[64 * 64];
  __shared__ u16 Vtc[64 * 64];
  __shared__ u16 Pl[8 * 32 * 64];
  const int b = blockIdx.x / NH, h = blockIdx.x % NH;
  const int tid = threadIdx.x, lane = tid & 63, w = tid >> 6;
  const int quad = lane >> 4, l16 = lane & 15;
  const int rowb = b * T_SEQ;

  bf16x8 qf[2][2];
#pragma unroll
  for (int mi = 0; mi < 2; mi++)
#pragma unroll
    for (int kk = 0; kk < 2; kk++)
      qf[mi][kk] = *(const bf16x8*)(qkv + (size_t)(rowb + w * 32 + mi * 16 + l16) * QKV_N +
                                    h * 64 + kk * 32 + quad * 8);

  f32x4 Oa[2][4];
  float mrun[2][4], lrun[2][4];
#pragma unroll
  for (int mi = 0; mi < 2; mi++) {
#pragma unroll
    for (int di = 0; di < 4; di++) Oa[mi][di] = (f32x4){0.f, 0.f, 0.f, 0.f};
#pragma unroll
    for (int r = 0; r < 4; r++) { mrun[mi][r] = -1e30f; lrun[mi][r] = 0.f; }
  }

  u16* Pw = &Pl[w * 2048];
  const int nch = (w >> 1) + 1;
  const int sr = tid >> 3, sseg = (tid & 7) * 8;

  for (int c = 0; c < 4; c++) {
    const int s0 = c * 64;
    __syncthreads();
    *(uint4*)&Kc[sr * 64 + sseg] =
        *(const uint4*)(qkv + (size_t)(rowb + s0 + sr) * QKV_N + 384 + h * 64 + sseg);
    {
      union { uint4 u; u16 us[8]; } tb;
      tb.u = *(const uint4*)(qkv + (size_t)(rowb + s0 + sr) * QKV_N + 768 + h * 64 + sseg);
#pragma unroll
      for (int j = 0; j < 8; j++) Vtc[(sseg + j) * 64 + sr] = tb.us[j];
    }
    __syncthreads();
    if (c >= nch) continue;

    f32x4 S[2][4];
    bf16x8 kf[4][2];
#pragma unroll
    for (int ni = 0; ni < 4; ni++)
#pragma unroll
      for (int kk = 0; kk < 2; kk++)
        kf[ni][kk] = *(const bf16x8*)&Kc[(ni * 16 + l16) * 64 + kk * 32 + quad * 8];
#pragma unroll
    for (int mi = 0; mi < 2; mi++)
#pragma unroll
      for (int ni = 0; ni < 4; ni++) {
        f32x4 z = (f32x4){0.f, 0.f, 0.f, 0.f};
        z = __builtin_amdgcn_mfma_f32_16x16x32_bf16(qf[mi][0], kf[ni][0], z, 0, 0, 0);
        S[mi][ni] = __builtin_amdgcn_mfma_f32_16x16x32_bf16(qf[mi][1], kf[ni][1], z, 0, 0, 0);
      }
    const bool diag = (c == nch - 1);
#pragma unroll
    for (int mi = 0; mi < 2; mi++)
#pragma unroll
      for (int ni = 0; ni < 4; ni++)
#pragma unroll
        for (int r = 0; r < 4; r++) {
          float xv = S[mi][ni][r] * 0.125f;
          if (diag) {
            int t = w * 32 + mi * 16 + quad * 4 + r;
            int s = s0 + ni * 16 + l16;
            if (s > t) xv = -1e30f;
          }
          S[mi][ni][r] = xv;
        }
#pragma unroll
    for (int mi = 0; mi < 2; mi++)
#pragma unroll
      for (int r = 0; r < 4; r++) {
        float mx = fmaxf(fmaxf(S[mi][0][r], S[mi][1][r]), fmaxf(S[mi][2][r], S[mi][3][r]));
        mx = fmaxf(mx, __shfl_xor(mx, 1));
        mx = fmaxf(mx, __shfl_xor(mx, 2));
        mx = fmaxf(mx, __shfl_xor(mx, 4));
        mx = fmaxf(mx, __shfl_xor(mx, 8));
        float mnew = fmaxf(mrun[mi][r], mx);
        float alpha = __expf(mrun[mi][r] - mnew);
        float ls = 0.f;
#pragma unroll
        for (int ni = 0; ni < 4; ni++) {
          float p = __expf(S[mi][ni][r] - mnew);
          S[mi][ni][r] = p; ls += p;
        }
        ls += __shfl_xor(ls, 1); ls += __shfl_xor(ls, 2);
        ls += __shfl_xor(ls, 4); ls += __shfl_xor(ls, 8);
        lrun[mi][r] = lrun[mi][r] * alpha + ls;
        mrun[mi][r] = mnew;
#pragma unroll
        for (int di = 0; di < 4; di++) Oa[mi][di][r] *= alpha;
      }
#pragma unroll
    for (int mi = 0; mi < 2; mi++)
#pragma unroll
      for (int ni = 0; ni < 4; ni++)
#pragma unroll
        for (int r = 0; r < 4; r++)
          Pw[(mi * 16 + quad * 4 + r) * 64 + ni * 16 + l16] = f2bf(S[mi][ni][r]);
    bf16x8 pf[2][2], vf[4][2];
#pragma unroll
    for (int mi = 0; mi < 2; mi++)
#pragma unroll
      for (int kk = 0; kk < 2; kk++)
        pf[mi][kk] = *(const bf16x8*)&Pw[(mi * 16 + l16) * 64 + kk * 32 + quad * 8];
#pragma unroll
    for (int di = 0; di < 4; di++)
#pragma unroll
      for (int kk = 0; kk < 2; kk++)
        vf[di][kk] = *(const bf16x8*)&Vtc[(di * 16 + l16) * 64 + kk * 32 + quad * 8];
#pragma unroll
    for (int mi = 0; mi < 2; mi++)
#pragma unroll
      for (int di = 0; di < 4; di++) {
        Oa[mi][di] = __builtin_amdgcn_mfma_f32_16x16x32_bf16(pf[mi][0], vf[di][0], Oa[mi][di], 0, 0, 0);
        Oa[mi][di] = __builtin_amdgcn_mfma_f32_16x16x32_bf16(pf[mi][1], vf[di][1], Oa[mi][di], 0, 0, 0);
      }
  }

#pragma unroll
  for (int mi = 0; mi < 2; mi++)
#pragma unroll
    for (int r = 0; r < 4; r++) {
      float inv = 1.f / lrun[mi][r];
      int t = w * 32 + mi * 16 + quad * 4 + r;
#pragma unroll
      for (int di = 0; di < 4; di++)
        att[(size_t)(rowb + t) * E_DIM + h * 64 + di * 16 + l16] = f2bf(Oa[mi][di][r] * inv);
    }
}

// ---------------- loss: grid-stride, 1 atomic per block ----------------
__global__ __launch_bounds__(256) void loss_k(const float* __restrict__ logits,
                                              const int* __restrict__ tgt,
                                              float* __restrict__ loss) {
  __shared__ float part[4];
  const int tid = threadIdx.x, lane = tid & 63, w = tid >> 6;
  const int wave_id = blockIdx.x * 4 + w;          // 512 blocks -> 2048 waves
  float acc = 0.f;
  for (int t = wave_id; t < BT; t += 2048) {
    const float* row = logits + (size_t)t * VOC;
    float a = row[lane];
    float b = (lane == 0) ? row[64] : -1e30f;
    float mx = fmaxf(a, b);
#pragma unroll
    for (int d = 1; d < 64; d <<= 1) mx = fmaxf(mx, __shfl_xor(mx, d));
    float sum = __expf(a - mx) + ((lane == 0) ? __expf(b - mx) : 0.f);
#pragma unroll
    for (int d = 1; d < 64; d <<= 1) sum += __shfl_xor(sum, d);
    if (lane == 0) acc += mx + __logf(sum) - row[tgt[t]];
  }
  if (lane == 0) part[w] = acc;
  __syncthreads();
  if (tid == 0)
    atomicAdd(loss, (part[0] + part[1] + part[2] + part[3]) * (1.f / (float)BT));
}

// ---------------- host ----------------
extern "C" void kernel_launch(void* const* d_in, const int* in_sizes, int n_in,
                              void* d_out, int out_size, void* d_ws, size_t ws_size,
                              hipStream_t stream) {
  (void)in_sizes; (void)n_in; (void)out_size; (void)ws_size;
  const int*   idx  = (const int*)d_in[0];
  const int*   tgt  = (const int*)d_in[1];
  const float* tok  = (const float*)d_in[2];
  const float* pos  = (const float*)d_in[3];
  const float* Wq   = (const float*)d_in[4];
  const float* Wk   = (const float*)d_in[5];
  const float* Wv   = (const float*)d_in[6];
  const float* Wo   = (const float*)d_in[7];
  const float* bo   = (const float*)d_in[8];
  const float* ln1s = (const float*)d_in[9];
  const float* ln1b = (const float*)d_in[10];
  const float* ln2s = (const float*)d_in[11];
  const float* ln2b = (const float*)d_in[12];
  const float* W1   = (const float*)d_in[13];
  const float* b1   = (const float*)d_in[14];
  const float* W2   = (const float*)d_in[15];
  const float* b2   = (const float*)d_in[16];
  const float* lnfs = (const float*)d_in[17];
  const float* lnfb = (const float*)d_in[18];
  const float* Wout = (const float*)d_in[19];
  const float* bout = (const float*)d_in[20];

  char* w = (char*)d_ws;
  u16* x      = (u16*)w;    w += (size_t)BT * E_DIM * 2;      // bf16 residual stream
  u16* hb     = (u16*)w;    w += (size_t)BT * E_DIM * 2;
  u16* attb   = (u16*)w;    w += (size_t)BT * E_DIM * 2;
  u16* big    = (u16*)w;    w += (size_t)BT * FF_DIM * 2;     // qkv / ff union
  u16* Wqkv_t = (u16*)w;    w += (size_t)NL * QKV_N * E_DIM * 2;
  u16* Wo_t   = (u16*)w;    w += (size_t)NL * E_DIM * E_DIM * 2;
  u16* W1_t   = (u16*)w;    w += (size_t)NL * FF_DIM * E_DIM * 2;
  u16* W2_t   = (u16*)w;    w += (size_t)NL * E_DIM * FF_DIM * 2;
  u16* Wout_t = (u16*)w;    w += (size_t)128 * E_DIM * 2;
  u16* qkv = big;
  u16* ff  = big;

  float* logits = (float*)d_out;
  float* loss   = logits + (size_t)BT * VOC;

  hipMemsetAsync(Wout_t, 0, 128 * E_DIM * 2, stream);
  transpose_t<<<dim3(12, 2, 36), 256, 0, stream>>>(Wq, Wqkv_t, 384, 64,
      24576, 442368, 6, 24576, 0);
  transpose_t<<<dim3(12, 2, 36), 256, 0, stream>>>(Wk, Wqkv_t, 384, 64,
      24576, 442368, 6, 24576, (long)384 * 384);
  transpose_t<<<dim3(12, 2, 36), 256, 0, stream>>>(Wv, Wqkv_t, 384, 64,
      24576, 442368, 6, 24576, (long)768 * 384);
  transpose_t<<<dim3(12, 12, 6), 256, 0, stream>>>(Wo, Wo_t, 384, 384,
      147456, 147456, 1, 0, 0);
  transpose_t<<<dim3(12, 48, 6), 256, 0, stream>>>(W1, W1_t, 384, 1536,
      589824, 589824, 1, 0, 0);
  transpose_t<<<dim3(48, 12, 6), 256, 0, stream>>>(W2, W2_t, 1536, 384,
      589824, 589824, 1, 0, 0);
  transpose_t<<<dim3(12, 3, 1), 256, 0, stream>>>(Wout, Wout_t, 384, 65,
      0, 0, 1, 0, 0);

  embed_k<<<6144, 256, 0, stream>>>(idx, tok, pos, x);

  for (int l = 0; l < NL; l++) {
    ln_k<<<8192, 256, 0, stream>>>(x, ln1s + l * E_DIM, ln1b + l * E_DIM, hb);
    gemm_d<<<dim3(256, 9), 256, 0, stream>>>(hb, Wqkv_t + (size_t)l * QKV_N * E_DIM,
                                             384, QKV_N, nullptr, nullptr, qkv, nullptr, 0);
    attn_k<<<768, 512, 0, stream>>>(qkv, attb);
    gemm_d<<<dim3(256, 3), 256, 0, stream>>>(attb, Wo_t + (size_t)l * E_DIM * E_DIM,
                                             384, E_DIM, bo + l * E_DIM, x, x, nullptr, 0);
    ln_k<<<8192, 256, 0, stream>>>(x, ln2s + l * E_DIM, ln2b + l * E_DIM, hb);
    gemm_d<<<dim3(256, 12), 256, 0, stream>>>(hb, W1_t + (size_t)l * FF_DIM * E_DIM,
                                              384, FF_DIM, b1 + l * FF_DIM, nullptr, ff, nullptr, 1);
    gemm_d<<<dim3(256, 3), 256, 0, stream>>>(ff, W2_t + (size_t)l * E_DIM * FF_DIM,
                                             1536, E_DIM, b2 + l * E_DIM, x, x, nullptr, 0);
  }
  ln_k<<<8192, 256, 0, stream>>>(x, lnfs, lnfb, hb);
  gemm_d<<<dim3(256, 1), 256, 0, stream>>>(hb, Wout_t, 384, VOC, bout, nullptr, nullptr, logits, 0);

  hipMemsetAsync(loss, 0, 4, stream);
  loss_k<<<512, 256, 0, stream>>>(logits, tgt, loss);
}

// Round 9
// 1799.939 us; speedup vs baseline: 1.9551x; 1.0008x over previous
//
#include <hip/hip_runtime.h>

// ---- problem constants ----
#define BT      32768     // B*T = 128*256
#define T_SEQ   256
#define E_DIM   384
#define NH      6
#define NL      6
#define VOC     65
#define FF_DIM  1536
#define QKV_N   1152      // 3*E

typedef short bf16x8 __attribute__((ext_vector_type(8)));   // 8 bf16 (4 VGPRs)
typedef float f32x4  __attribute__((ext_vector_type(4)));
typedef unsigned short u16;

typedef const unsigned int __attribute__((address_space(1))) gu32;
typedef unsigned int       __attribute__((address_space(3))) lu32;

__device__ __forceinline__ u16 f2bf(float x) {              // RNE fp32->bf16
  unsigned u = __builtin_bit_cast(unsigned, x);
  u += 0x7fffu + ((u >> 16) & 1u);
  return (u16)(u >> 16);
}
__device__ __forceinline__ float bf2f(u16 v) {
  unsigned u = ((unsigned)v) << 16;
  return __builtin_bit_cast(float, u);
}

__device__ __forceinline__ void load_lds_16(const void* g, void* l) {
  __builtin_amdgcn_global_load_lds((gu32*)g, (lu32*)l, 16, 0, 0);
}

// ---------------- unified LDS-tiled transpose: src[b][R][C] fp32 -> dst bf16 [.. C][R] ----------------
__global__ __launch_bounds__(256) void transpose_t(
    const float* __restrict__ src, u16* __restrict__ dst, int R, int C,
    long sbs, long dbs_outer, int inner, long dbs_inner, long dbase) {
  __shared__ float t[32][33];
  const int b = blockIdx.z;
  const float* s = src + (long)b * sbs;
  u16* d = dst + dbase + (long)(b / inner) * dbs_outer + (long)(b % inner) * dbs_inner;
  const int r0 = blockIdx.x * 32, c0 = blockIdx.y * 32;
  const int tx = threadIdx.x & 31, ty = threadIdx.x >> 5;   // 32 x 8
#pragma unroll
  for (int i = 0; i < 4; i++) {
    int rr = ty + i * 8;
    int r = r0 + rr, c = c0 + tx;
    if (r < R && c < C) t[rr][tx] = s[(long)r * C + c];
  }
  __syncthreads();
#pragma unroll
  for (int i = 0; i < 4; i++) {
    int cc = ty + i * 8;
    int c = c0 + cc, r = r0 + tx;
    if (c < C && r < R) d[(long)c * R + r] = f2bf(t[tx][cc]);
  }
}

// ---------------- embedding (bf16 out) ----------------
__global__ __launch_bounds__(256) void embed_k(const int* __restrict__ idx,
                                               const float* __restrict__ tok,
                                               const float* __restrict__ pos,
                                               u16* __restrict__ x) {
  int i = blockIdx.x * 256 + threadIdx.x;        // over BT*48 groups of 8
  int bt = i / 48, q = i - bt * 48;
  int t = bt & 255;
  const float4* tp = (const float4*)(tok + (size_t)idx[bt] * E_DIM + q * 8);
  const float4* pp = (const float4*)(pos + (size_t)t * E_DIM + q * 8);
  float4 a0 = tp[0], a1 = tp[1], p0 = pp[0], p1 = pp[1];
  u16 o[8];
  o[0] = f2bf(a0.x + p0.x); o[1] = f2bf(a0.y + p0.y);
  o[2] = f2bf(a0.z + p0.z); o[3] = f2bf(a0.w + p0.w);
  o[4] = f2bf(a1.x + p1.x); o[5] = f2bf(a1.y + p1.y);
  o[6] = f2bf(a1.z + p1.z); o[7] = f2bf(a1.w + p1.w);
  *(bf16x8*)(x + (size_t)bt * E_DIM + q * 8) = *(bf16x8*)o;
}

// ---------------- layernorm (bf16 in -> bf16 out, fp32 math) ----------------
__global__ __launch_bounds__(256) void ln_k(const u16* __restrict__ x,
                                            const float* __restrict__ gam,
                                            const float* __restrict__ bet,
                                            u16* __restrict__ out) {
  int tid = threadIdx.x, lane = tid & 63, w = tid >> 6;
  size_t token = (size_t)blockIdx.x * 4 + w;
  const u16* xr = x + token * E_DIM;
  u16 raw[6];
  *(uint2*)raw          = *(const uint2*)(xr + 4 * lane);
  *(unsigned*)(raw + 4) = *(const unsigned*)(xr + 256 + 2 * lane);
  float v[6]; float s = 0.f;
#pragma unroll
  for (int i = 0; i < 6; i++) { v[i] = bf2f(raw[i]); s += v[i]; }
#pragma unroll
  for (int d = 1; d < 64; d <<= 1) s += __shfl_xor(s, d);
  float mean = s * (1.f / E_DIM);
  float q = 0.f;
#pragma unroll
  for (int i = 0; i < 6; i++) { float d0 = v[i] - mean; q += d0 * d0; }
#pragma unroll
  for (int d = 1; d < 64; d <<= 1) q += __shfl_xor(q, d);
  float r = rsqrtf(q * (1.f / E_DIM) + 1e-5f);
  int e[6] = {4 * lane, 4 * lane + 1, 4 * lane + 2, 4 * lane + 3,
              256 + 2 * lane, 256 + 2 * lane + 1};
  u16 o[6];
#pragma unroll
  for (int i = 0; i < 6; i++)
    o[i] = f2bf((v[i] - mean) * r * gam[e[i]] + bet[e[i]]);
  u16* orow = out + token * E_DIM;
  *(uint2*)(orow + 4 * lane)          = *(uint2*)o;
  *(unsigned*)(orow + 256 + 2 * lane) = *(unsigned*)(o + 4);
}

// ---------------- dbuf + swizzled DMA MFMA GEMM: C = A[M][K] @ Bt[N][K]^T (bf16) ------
// 128x128 tile, BK=32, double-buffered DMA staging (R3/R7 structure). Corrected bank
// swizzle: fetched chunk = (lane&3)^((lane>>3)&3) -> chunk c of within-group row r'
// lands at slot c^((r'>>1)&3); fragment read slot = quad^((l16>>1)&3). Combined with
// the row-parity term (stride 16 dwords) this gives uniform 8 accesses/bank (b128 min).
__global__ __launch_bounds__(256) void gemm_d(
    const u16* __restrict__ A, const u16* __restrict__ Bt, int K, int Nstore,
    const float* __restrict__ bias, const u16* __restrict__ resid,
    u16* __restrict__ outH, float* __restrict__ outF, int relu) {
  __shared__ u16 smem[16384];                 // As[2][128][32] | Bs[2][128][32]
  u16* As = smem;
  u16* Bs = smem + 8192;
  const int tid = threadIdx.x, lane = tid & 63, wv = tid >> 6;
  const int quad = lane >> 4, l16 = lane & 15;
  const int m0 = blockIdx.x * 128, n0 = blockIdx.y * 128;
  const int wm = (wv & 1) * 64, wn = (wv >> 1) * 64;

  const int lrow = lane >> 2;                        // within-group row 0..15
  const int lchunk = (lane & 3) ^ ((lane >> 3) & 3); // swizzled source chunk

  f32x4 acc[4][4];
#pragma unroll
  for (int i = 0; i < 4; i++)
#pragma unroll
    for (int j = 0; j < 4; j++) acc[i][j] = (f32x4){0.f, 0.f, 0.f, 0.f};

  auto stage = [&](int sel, int k0) {
#pragma unroll
    for (int j = 0; j < 2; j++) {
      int rid = wv * 2 + j;                    // 8 groups of 16 rows
      int r = rid * 16 + lrow;
      load_lds_16(A + (size_t)(m0 + r) * K + k0 + lchunk * 8, &As[sel * 4096 + rid * 512]);
      load_lds_16(Bt + (size_t)(n0 + r) * K + k0 + lchunk * 8, &Bs[sel * 4096 + rid * 512]);
    }
  };

  const int NK = K >> 5;
  stage(0, 0);
  __syncthreads();                             // drain prologue DMA
  const int slot = (quad ^ ((l16 >> 1) & 3)) * 8;    // un-swizzle for fragment read
  for (int kt = 0; kt < NK; kt++) {
    const int cur = kt & 1;
    if (kt + 1 < NK) stage(cur ^ 1, (kt + 1) * 32);  // prefetch; drain at loop barrier
    const u16* Ab = As + cur * 4096;
    const u16* Bb = Bs + cur * 4096;
    bf16x8 af[4], bfr[4];
#pragma unroll
    for (int i = 0; i < 4; i++) af[i]  = *(const bf16x8*)&Ab[(wm + i * 16 + l16) * 32 + slot];
#pragma unroll
    for (int j = 0; j < 4; j++) bfr[j] = *(const bf16x8*)&Bb[(wn + j * 16 + l16) * 32 + slot];
#pragma unroll
    for (int i = 0; i < 4; i++)
#pragma unroll
      for (int j = 0; j < 4; j++)
        acc[i][j] = __builtin_amdgcn_mfma_f32_16x16x32_bf16(af[i], bfr[j], acc[i][j], 0, 0, 0);
    __syncthreads();   // drains prefetch (after compute overlap) + guards dbuf reuse
  }

  if (outH) {
#pragma unroll
    for (int p = 0; p < 4; p++) {
      if (p) __syncthreads();
      if ((wv >> 1) == (p >> 1)) {
#pragma unroll
        for (int jj = 0; jj < 2; jj++) {
          int j = (p & 1) * 2 + jj;
          int gn = n0 + wn + j * 16 + l16;
          float bv = bias ? bias[gn] : 0.f;
          int lcol = jj * 16 + l16;
#pragma unroll
          for (int i = 0; i < 4; i++)
#pragma unroll
            for (int r = 0; r < 4; r++) {
              float v = acc[i][j][r] + bv;
              if (relu) v = fmaxf(v, 0.f);
              smem[(wm + i * 16 + quad * 4 + r) * 36 + lcol] = f2bf(v);
            }
        }
      }
      __syncthreads();
      const int gc0 = n0 + p * 32;
#pragma unroll
      for (int s = 0; s < 4; s++) {
        int row = s * 32 + (tid >> 3);
        int seg = (tid & 7) * 4;
        u16 pk[4];
        *(uint2*)pk = *(const uint2*)&smem[row * 36 + seg];
        size_t o = (size_t)(m0 + row) * Nstore + gc0 + seg;
        if (resid) {
          u16 rv[4];
          *(uint2*)rv = *(const uint2*)&resid[o];
#pragma unroll
          for (int q2 = 0; q2 < 4; q2++) pk[q2] = f2bf(bf2f(pk[q2]) + bf2f(rv[q2]));
        }
        *(uint2*)&outH[o] = *(uint2*)pk;
      }
    }
  } else {
#pragma unroll
    for (int j = 0; j < 4; j++) {
      const int gn = n0 + wn + j * 16 + l16;
      if (gn < Nstore) {
        const float bv = bias ? bias[gn] : 0.f;
#pragma unroll
        for (int i = 0; i < 4; i++)
#pragma unroll
          for (int r = 0; r < 4; r++) {
            const int gm = m0 + wm + i * 16 + quad * 4 + r;
            outF[(size_t)gm * Nstore + gn] = acc[i][j][r] + bv;
          }
      }
    }
  }
}

// ---------------- fused causal attention (load-balanced, bank-swizzled) ----------------
// Wave w owns Q-tiles {w, 15-w} (16 rows each): causal work = exactly 5 tile-chunks per
// wave (was 2..8 -> barrier-bound at 8). Kc/Vtc/P stored with chunk-XOR swizzle
// (slot = chunk ^ key(row)) -> conflict-free writes AND b128 reads, 16B alignment kept.
__global__ __launch_bounds__(512) void attn_k(const u16* __restrict__ qkv,
                                              u16* __restrict__ att) {
  __shared__ u16 Kc[64 * 64];    // K chunk  [s][d],  slot = (d>>3) ^ (s&7) ^ ((s>>3)&7)
  __shared__ u16 Vtc[64 * 64];   // V^T chunk [d][s], slot = (s>>3) ^ (d&7) ^ ((d>>3)&7)
  __shared__ u16 Pl[8 * 16 * 64];// per-wave P [16][64], slot = ch ^ (row>>2 | (row&1)<<2)
  const int b = blockIdx.x / NH, h = blockIdx.x % NH;
  const int tid = threadIdx.x, lane = tid & 63, w = tid >> 6;
  const int quad = lane >> 4, l16 = lane & 15;
  const int rowb = b * T_SEQ;
  const int tiles[2] = {w, 15 - w};

  // Q fragments (A-layout) from global, resident all kernel
  bf16x8 qf[2][2];
#pragma unroll
  for (int ti = 0; ti < 2; ti++)
#pragma unroll
    for (int kk = 0; kk < 2; kk++)
      qf[ti][kk] = *(const bf16x8*)(qkv + (size_t)(rowb + tiles[ti] * 16 + l16) * QKV_N +
                                    h * 64 + kk * 32 + quad * 8);

  f32x4 Oa[2][4];
  float mrun[2][4], lrun[2][4];
#pragma unroll
  for (int ti = 0; ti < 2; ti++) {
#pragma unroll
    for (int di = 0; di < 4; di++) Oa[ti][di] = (f32x4){0.f, 0.f, 0.f, 0.f};
#pragma unroll
    for (int r = 0; r < 4; r++) { mrun[ti][r] = -1e30f; lrun[ti][r] = 0.f; }
  }

  u16* Pw = &Pl[w * 1024];
  const int sr = tid >> 3, sseg = tid & 7;       // sr: s-row 0..63, sseg: 16B chunk 0..7
  const int kst = sseg ^ (sr & 7) ^ ((sr >> 3) & 7);

  for (int c = 0; c < 4; c++) {
    const int s0 = c * 64;
    __syncthreads();                             // WAR
    // stage K chunk (coalesced uint4, swizzled slot)
    *(uint4*)&Kc[sr * 64 + kst * 8] =
        *(const uint4*)(qkv + (size_t)(rowb + s0 + sr) * QKV_N + 384 + h * 64 + sseg * 8);
    // stage V^T chunk (scalar scatter, swizzled slot -> conflict-free)
    {
      union { uint4 u; u16 us[8]; } tb;
      tb.u = *(const uint4*)(qkv + (size_t)(rowb + s0 + sr) * QKV_N + 768 + h * 64 + sseg * 8);
#pragma unroll
      for (int j = 0; j < 8; j++) {
        int d = sseg * 8 + j;
        int vst = (sr >> 3) ^ (d & 7) ^ ((d >> 3) & 7);
        Vtc[d * 64 + vst * 8 + (sr & 7)] = tb.us[j];
      }
    }
    __syncthreads();                             // RAW

    bf16x8 kf[4][2], vf[4][2];
    bool loaded = false;
#pragma unroll
    for (int ti = 0; ti < 2; ti++) {
      const int t = tiles[ti];
      if (t < 4 * c) continue;                   // causal: tile needs chunks 0..t/4
      if (!loaded) {
        loaded = true;
#pragma unroll
        for (int ni = 0; ni < 4; ni++)
#pragma unroll
          for (int kk = 0; kk < 2; kk++) {
            int srow = ni * 16 + l16;
            int ks = (kk * 4 + quad) ^ (srow & 7) ^ ((srow >> 3) & 7);
            kf[ni][kk] = *(const bf16x8*)&Kc[srow * 64 + ks * 8];
            int drow = ni * 16 + l16;            // same index math for V^T rows
            int vs = (kk * 4 + quad) ^ (drow & 7) ^ ((drow >> 3) & 7);
            vf[ni][kk] = *(const bf16x8*)&Vtc[drow * 64 + vs * 8];
          }
      }
      // S = Q K^T
      f32x4 S[4];
#pragma unroll
      for (int ni = 0; ni < 4; ni++) {
        f32x4 z = (f32x4){0.f, 0.f, 0.f, 0.f};
        z = __builtin_amdgcn_mfma_f32_16x16x32_bf16(qf[ti][0], kf[ni][0], z, 0, 0, 0);
        S[ni] = __builtin_amdgcn_mfma_f32_16x16x32_bf16(qf[ti][1], kf[ni][1], z, 0, 0, 0);
      }
      const bool diag = ((t >> 2) == c);
#pragma unroll
      for (int ni = 0; ni < 4; ni++)
#pragma unroll
        for (int r = 0; r < 4; r++) {
          float xv = S[ni][r] * 0.125f;          // DH^-0.5
          if (diag) {
            int trow = t * 16 + quad * 4 + r;
            int s = s0 + ni * 16 + l16;
            if (s > trow) xv = -1e30f;
          }
          S[ni][r] = xv;
        }
      // online softmax (row in 16 lanes of one quad)
#pragma unroll
      for (int r = 0; r < 4; r++) {
        float mx = fmaxf(fmaxf(S[0][r], S[1][r]), fmaxf(S[2][r], S[3][r]));
        mx = fmaxf(mx, __shfl_xor(mx, 1));
        mx = fmaxf(mx, __shfl_xor(mx, 2));
        mx = fmaxf(mx, __shfl_xor(mx, 4));
        mx = fmaxf(mx, __shfl_xor(mx, 8));
        float mnew = fmaxf(mrun[ti][r], mx);
        float alpha = __expf(mrun[ti][r] - mnew);
        float ls = 0.f;
#pragma unroll
        for (int ni = 0; ni < 4; ni++) {
          float p = __expf(S[ni][r] - mnew);
          S[ni][r] = p; ls += p;
        }
        ls += __shfl_xor(ls, 1); ls += __shfl_xor(ls, 2);
        ls += __shfl_xor(ls, 4); ls += __shfl_xor(ls, 8);
        lrun[ti][r] = lrun[ti][r] * alpha + ls;
        mrun[ti][r] = mnew;
#pragma unroll
        for (int di = 0; di < 4; di++) Oa[ti][di][r] *= alpha;
      }
      // P -> per-wave LDS (C-layout write, swizzle key = row>>2 | (row&1)<<2)
#pragma unroll
      for (int ni = 0; ni < 4; ni++)
#pragma unroll
        for (int r = 0; r < 4; r++) {
          int ch = 2 * ni + (l16 >> 3);
          int st = ch ^ (quad | ((r & 1) << 2));
          Pw[(quad * 4 + r) * 64 + st * 8 + (l16 & 7)] = f2bf(S[ni][r]);
        }
      // A-layout read-back (compiler inserts lgkmcnt wait; wave-private, no barrier)
      bf16x8 pf[2];
#pragma unroll
      for (int kk = 0; kk < 2; kk++) {
        int key = (l16 >> 2) | ((l16 & 1) << 2);
        int st = (kk * 4 + quad) ^ key;
        pf[kk] = *(const bf16x8*)&Pw[l16 * 64 + st * 8];
      }
      // O += P V
#pragma unroll
      for (int di = 0; di < 4; di++) {
        Oa[ti][di] = __builtin_amdgcn_mfma_f32_16x16x32_bf16(pf[0], vf[di][0], Oa[ti][di], 0, 0, 0);
        Oa[ti][di] = __builtin_amdgcn_mfma_f32_16x16x32_bf16(pf[1], vf[di][1], Oa[ti][di], 0, 0, 0);
      }
    }
  }

  // normalize + store
#pragma unroll
  for (int ti = 0; ti < 2; ti++)
#pragma unroll
    for (int r = 0; r < 4; r++) {
      float inv = 1.f / lrun[ti][r];
      int trow = tiles[ti] * 16 + quad * 4 + r;
#pragma unroll
      for (int di = 0; di < 4; di++)
        att[(size_t)(rowb + trow) * E_DIM + h * 64 + di * 16 + l16] = f2bf(Oa[ti][di][r] * inv);
    }
}

// ---------------- loss: grid-stride, 1 atomic per block ----------------
__global__ __launch_bounds__(256) void loss_k(const float* __restrict__ logits,
                                              const int* __restrict__ tgt,
                                              float* __restrict__ loss) {
  __shared__ float part[4];
  const int tid = threadIdx.x, lane = tid & 63, w = tid >> 6;
  const int wave_id = blockIdx.x * 4 + w;          // 512 blocks -> 2048 waves
  float acc = 0.f;
  for (int t = wave_id; t < BT; t += 2048) {
    const float* row = logits + (size_t)t * VOC;
    float a = row[lane];
    float b = (lane == 0) ? row[64] : -1e30f;
    float mx = fmaxf(a, b);
#pragma unroll
    for (int d = 1; d < 64; d <<= 1) mx = fmaxf(mx, __shfl_xor(mx, d));
    float sum = __expf(a - mx) + ((lane == 0) ? __expf(b - mx) : 0.f);
#pragma unroll
    for (int d = 1; d < 64; d <<= 1) sum += __shfl_xor(sum, d);
    if (lane == 0) acc += mx + __logf(sum) - row[tgt[t]];
  }
  if (lane == 0) part[w] = acc;
  __syncthreads();
  if (tid == 0)
    atomicAdd(loss, (part[0] + part[1] + part[2] + part[3]) * (1.f / (float)BT));
}

// ---------------- host ----------------
extern "C" void kernel_launch(void* const* d_in, const int* in_sizes, int n_in,
                              void* d_out, int out_size, void* d_ws, size_t ws_size,
                              hipStream_t stream) {
  (void)in_sizes; (void)n_in; (void)out_size; (void)ws_size;
  const int*   idx  = (const int*)d_in[0];
  const int*   tgt  = (const int*)d_in[1];
  const float* tok  = (const float*)d_in[2];
  const float* pos  = (const float*)d_in[3];
  const float* Wq   = (const float*)d_in[4];
  const float* Wk   = (const float*)d_in[5];
  const float* Wv   = (const float*)d_in[6];
  const float* Wo   = (const float*)d_in[7];
  const float* bo   = (const float*)d_in[8];
  const float* ln1s = (const float*)d_in[9];
  const float* ln1b = (const float*)d_in[10];
  const float* ln2s = (const float*)d_in[11];
  const float* ln2b = (const float*)d_in[12];
  const float* W1   = (const float*)d_in[13];
  const float* b1   = (const float*)d_in[14];
  const float* W2   = (const float*)d_in[15];
  const float* b2   = (const float*)d_in[16];
  const float* lnfs = (const float*)d_in[17];
  const float* lnfb = (const float*)d_in[18];
  const float* Wout = (const float*)d_in[19];
  const float* bout = (const float*)d_in[20];

  char* w = (char*)d_ws;
  u16* x      = (u16*)w;    w += (size_t)BT * E_DIM * 2;      // bf16 residual stream
  u16* hb     = (u16*)w;    w += (size_t)BT * E_DIM * 2;
  u16* attb   = (u16*)w;    w += (size_t)BT * E_DIM * 2;
  u16* big    = (u16*)w;    w += (size_t)BT * FF_DIM * 2;     // qkv / ff union
  u16* Wqkv_t = (u16*)w;    w += (size_t)NL * QKV_N * E_DIM * 2;
  u16* Wo_t   = (u16*)w;    w += (size_t)NL * E_DIM * E_DIM * 2;
  u16* W1_t   = (u16*)w;    w += (size_t)NL * FF_DIM * E_DIM * 2;
  u16* W2_t   = (u16*)w;    w += (size_t)NL * E_DIM * FF_DIM * 2;
  u16* Wout_t = (u16*)w;    w += (size_t)128 * E_DIM * 2;
  u16* qkv = big;
  u16* ff  = big;

  float* logits = (float*)d_out;
  float* loss   = logits + (size_t)BT * VOC;

  hipMemsetAsync(Wout_t, 0, 128 * E_DIM * 2, stream);
  transpose_t<<<dim3(12, 2, 36), 256, 0, stream>>>(Wq, Wqkv_t, 384, 64,
      24576, 442368, 6, 24576, 0);
  transpose_t<<<dim3(12, 2, 36), 256, 0, stream>>>(Wk, Wqkv_t, 384, 64,
      24576, 442368, 6, 24576, (long)384 * 384);
  transpose_t<<<dim3(12, 2, 36), 256, 0, stream>>>(Wv, Wqkv_t, 384, 64,
      24576, 442368, 6, 24576, (long)768 * 384);
  transpose_t<<<dim3(12, 12, 6), 256, 0, stream>>>(Wo, Wo_t, 384, 384,
      147456, 147456, 1, 0, 0);
  transpose_t<<<dim3(12, 48, 6), 256, 0, stream>>>(W1, W1_t, 384, 1536,
      589824, 589824, 1, 0, 0);
  transpose_t<<<dim3(48, 12, 6), 256, 0, stream>>>(W2, W2_t, 1536, 384,
      589824, 589824, 1, 0, 0);
  transpose_t<<<dim3(12, 3, 1), 256, 0, stream>>>(Wout, Wout_t, 384, 65,
      0, 0, 1, 0, 0);

  embed_k<<<6144, 256, 0, stream>>>(idx, tok, pos, x);

  for (int l = 0; l < NL; l++) {
    ln_k<<<8192, 256, 0, stream>>>(x, ln1s + l * E_DIM, ln1b + l * E_DIM, hb);
    gemm_d<<<dim3(256, 9), 256, 0, stream>>>(hb, Wqkv_t + (size_t)l * QKV_N * E_DIM,
                                             384, QKV_N, nullptr, nullptr, qkv, nullptr, 0);
    attn_k<<<768, 512, 0, stream>>>(qkv, attb);
    gemm_d<<<dim3(256, 3), 256, 0, stream>>>(attb, Wo_t + (size_t)l * E_DIM * E_DIM,
                                             384, E_DIM, bo + l * E_DIM, x, x, nullptr, 0);
    ln_k<<<8192, 256, 0, stream>>>(x, ln2s + l * E_DIM, ln2b + l * E_DIM, hb);
    gemm_d<<<dim3(256, 12), 256, 0, stream>>>(hb, W1_t + (size_t)l * FF_DIM * E_DIM,
                                              384, FF_DIM, b1 + l * FF_DIM, nullptr, ff, nullptr, 1);
    gemm_d<<<dim3(256, 3), 256, 0, stream>>>(ff, W2_t + (size_t)l * E_DIM * FF_DIM,
                                             1536, E_DIM, b2 + l * E_DIM, x, x, nullptr, 0);
  }
  ln_k<<<8192, 256, 0, stream>>>(x, lnfs, lnfb, hb);
  gemm_d<<<dim3(256, 1), 256, 0, stream>>>(hb, Wout_t, 384, VOC, bout, nullptr, nullptr, logits, 0);

  hipMemsetAsync(loss, 0, 4, stream);
  loss_k<<<512, 256, 0, stream>>>(logits, tgt, loss);
}